// Round 11
// baseline (292.417 us; speedup 1.0000x reference)
//
#include <hip/hip_runtime.h>
#include <math.h>

typedef __attribute__((ext_vector_type(8))) short short8;
typedef __attribute__((ext_vector_type(4))) float f32x4;
typedef __attribute__((ext_vector_type(16))) float f32x16;
typedef __attribute__((ext_vector_type(4))) float fvec4;
typedef __attribute__((ext_vector_type(4))) unsigned short us4;
typedef __attribute__((ext_vector_type(2))) unsigned int uint2v;

#define DI __device__ __forceinline__
#define BARX asm volatile("s_barrier" ::: "memory")
#define WAITV8 asm volatile("s_waitcnt vmcnt(8)" ::: "memory")
#define WAITV6 asm volatile("s_waitcnt vmcnt(6)" ::: "memory")
#define WAITV4 asm volatile("s_waitcnt vmcnt(4)" ::: "memory")
#define WAITV0 asm volatile("s_waitcnt vmcnt(0)" ::: "memory")
#define WAITL0 asm volatile("s_waitcnt lgkmcnt(0)" ::: "memory")
#define SCHED0 __builtin_amdgcn_sched_barrier(0)

constexpr int BB = 2, SS = 2048, HIDc = 2048, NHc = 16, HDc = 128;
constexpr int MT = BB * SS;     // 4096 tokens
constexpr int KC = HIDc;        // 2048 inner dim

// ---- workspace layout (bytes) ----
constexpr size_t OFF_HB  = 0;                                      // H bf16   [4096][2048]
constexpr size_t OFF_WB  = OFF_HB + (size_t)MT * KC * 2;           // W bf16   4x[2048][2048]
constexpr size_t OFF_Q   = OFF_WB + (size_t)4 * HIDc * KC * 2;     // Q bf16   [b][h][s][d]
constexpr size_t OFF_K   = OFF_Q  + (size_t)BB * NHc * SS * HDc * 2;
constexpr size_t OFF_V   = OFF_K  + (size_t)BB * NHc * SS * HDc * 2; // V bf16 [b][h][d][s]
constexpr size_t OFF_ATT = OFF_V  + (size_t)BB * NHc * SS * HDc * 2; // attn bf16 [b*s][hid]
constexpr size_t OFF_COS = OFF_ATT + (size_t)MT * HIDc * 2;
constexpr size_t OFF_SIN = OFF_COS + (size_t)SS * 32 * 4;
constexpr size_t WS_NEED = OFF_SIN + (size_t)SS * 32 * 4;          // ~118 MB

DI float bf2f(unsigned short u) { union { unsigned u; float f; } v; v.u = (unsigned)u << 16; return v.f; }
DI unsigned short f2bf(float f) {
  union { float f; unsigned u; } v; v.f = f;
  unsigned r = v.u + 0x7fffu + ((v.u >> 16) & 1u);
  return (unsigned short)(r >> 16);
}

DI void gload_lds16(const void* g, void* l) {
  __builtin_amdgcn_global_load_lds((const __attribute__((address_space(1))) void*)g,
                                   (__attribute__((address_space(3))) void*)l, 16, 0, 0);
}

DI unsigned cvtpk_bf16(float lo, float hi_) {
  unsigned r;
  asm("v_cvt_pk_bf16_f32 %0, %1, %2" : "=v"(r) : "v"(lo), "v"(hi_));
  return r;
}

// ---------------------------------------------------------------------------
// 1) fp32 -> bf16 convert of H and the 4 weights into one contiguous region
// ---------------------------------------------------------------------------
__global__ void __launch_bounds__(256) cvt_kernel(
    const float* __restrict__ H,  const float* __restrict__ W0,
    const float* __restrict__ W1, const float* __restrict__ W2,
    const float* __restrict__ W3, unsigned short* __restrict__ dst)
{
  constexpr size_t HN = (size_t)MT * KC;      // 8388608
  constexpr size_t WN = (size_t)HIDc * KC;    // 4194304 = 2^22
  size_t e0 = ((size_t)blockIdx.x * 256 + threadIdx.x) * 8;
  const float* src; size_t off;
  if (e0 < HN) { src = H; off = e0; }
  else {
    size_t t = e0 - HN; int a = (int)(t >> 22);
    src = (a == 0) ? W0 : (a == 1) ? W1 : (a == 2) ? W2 : W3;
    off = t & (WN - 1);
  }
  fvec4 v0 = *(const fvec4*)(src + off);
  fvec4 v1 = *(const fvec4*)(src + off + 4);
  short8 o;
  o[0] = (short)f2bf(v0[0]); o[1] = (short)f2bf(v0[1]);
  o[2] = (short)f2bf(v0[2]); o[3] = (short)f2bf(v0[3]);
  o[4] = (short)f2bf(v1[0]); o[5] = (short)f2bf(v1[1]);
  o[6] = (short)f2bf(v1[2]); o[7] = (short)f2bf(v1[3]);
  *(short8*)(dst + e0) = o;
}

// ---------------------------------------------------------------------------
// 2) RoPE tables
// ---------------------------------------------------------------------------
__global__ void __launch_bounds__(256) rope_tab_kernel(float* __restrict__ cosT,
                                                       float* __restrict__ sinT)
{
  int idx = blockIdx.x * 256 + threadIdx.x;   // S*32 = 65536
  int t = idx >> 5, fi = idx & 31;
  float inv = powf(10000.0f, -(float)fi * (1.0f / 32.0f));
  float ang = (float)t * inv;
  cosT[idx] = cosf(ang);
  sinT[idx] = sinf(ang);
}

// ---------------------------------------------------------------------------
// 3a) QKV GEMM, m201-class: BM=256 BN=256 BK=32, 512 thr (8 waves 2m x 4n,
//     per-wave 128x64, acc 128 VGPR, B-frags held across K-tile).
//     4-deep LDS ring (128 KiB), prefetch distance 3, counted vmcnt(8),
//     2 phases/K-tile x 16-MFMA clusters (8 barriers per K=64, m201 density).
//     Swizzle: 16B-chunk position = chunk ^ (row&3) both sides (involution).
//     Folded N=6144 epilogue: z = col>>11 (Q,K [b][h][s][d]; V [b][h][d][s]).
// ---------------------------------------------------------------------------
template<int NBX>
__global__ void __launch_bounds__(512, 2) gemmQKV(
    const unsigned short* __restrict__ A,
    const unsigned short* __restrict__ Bw,
    void* __restrict__ dq, void* __restrict__ dk, void* __restrict__ dv)
{
  __shared__ __align__(16) unsigned short Al[4][256 * 32];
  __shared__ __align__(16) unsigned short Bl[4][256 * 32];
  const int tid = threadIdx.x, lane = tid & 63, w = tid >> 6;
  const int wm = w >> 2, wn = w & 3;
  const int ln15 = lane & 15, lq = lane >> 4;

  const int xcd = blockIdx.x & 7, idx = blockIdx.x >> 3;
  const int by = xcd * 2 + idx / NBX, bx = idx % NBX;
  const int m0 = by * 256, n0 = bx * 256;

  // staging constants: 2 chunks per thread per tensor per K-tile
  const unsigned short* asrc[2];
  const unsigned short* bsrc[2];
#pragma unroll
  for (int l = 0; l < 2; ++l) {
    int c = l * 512 + tid;             // 0..1023
    int row = c >> 2, sp = c & 3;
    int sc = sp ^ (row & 3);           // involution with read swizzle
    asrc[l] = A  + (size_t)(m0 + row) * KC + sc * 8;
    bsrc[l] = Bw + (size_t)(n0 + row) * KC + sc * 8;
  }

  const int slA = (lq ^ (ln15 & 3)) * 8;
  int rA[8], rB[4];
#pragma unroll
  for (int i = 0; i < 8; ++i) rA[i] = (wm * 128 + i * 16 + ln15) * 32;
#pragma unroll
  for (int j = 0; j < 4; ++j) rB[j] = (wn * 64 + j * 16 + ln15) * 32;

  constexpr int NT = KC / 32;   // 64
  auto stA = [&](int kt, int l) {
    gload_lds16(asrc[l] + (size_t)kt * 32, &Al[kt & 3][(size_t)(l * 512 + w * 64) * 8]);
  };
  auto stB = [&](int kt, int l) {
    gload_lds16(bsrc[l] + (size_t)kt * 32, &Bl[kt & 3][(size_t)(l * 512 + w * 64) * 8]);
  };

  // prologue: stage tiles 0,1,2 (12 loads); retire tile 0 (vmcnt 8); barrier
  stA(0, 0); stA(0, 1); stB(0, 0); stB(0, 1);
  stA(1, 0); stA(1, 1); stB(1, 0); stB(1, 1);
  stA(2, 0); stA(2, 1); stB(2, 0); stB(2, 1);
  WAITV8; BARX;

  f32x4 acc[8][4] = {};
  for (int kt = 0; kt < NT; ++kt) {
    const unsigned short* Ac = &Al[kt & 3][0];
    const unsigned short* Bc = &Bl[kt & 3][0];
    const bool pf = (kt + 3 < NT);
    short8 af[4], bfr[4];

    // ---- phase 0: read B(all)+A(m0..3), stage A of kt+3, 16 MFMA ----
#pragma unroll
    for (int j = 0; j < 4; ++j) bfr[j] = *(const short8*)&Bc[rB[j] + slA];
#pragma unroll
    for (int i = 0; i < 4; ++i) af[i] = *(const short8*)&Ac[rA[i] + slA];
    if (pf) { stA(kt + 3, 0); stA(kt + 3, 1); }
    BARX;
    WAITL0; SCHED0;
    __builtin_amdgcn_s_setprio(1);
#pragma unroll
    for (int i = 0; i < 4; ++i)
#pragma unroll
      for (int j = 0; j < 4; ++j)
        acc[i][j] = __builtin_amdgcn_mfma_f32_16x16x32_bf16(af[i], bfr[j], acc[i][j], 0, 0, 0);
    __builtin_amdgcn_s_setprio(0);
    BARX;

    // ---- phase 1: read A(m4..7), stage B of kt+3, 16 MFMA, counted vmcnt ----
#pragma unroll
    for (int i = 0; i < 4; ++i) af[i] = *(const short8*)&Ac[rA[4 + i] + slA];
    if (pf) { stB(kt + 3, 0); stB(kt + 3, 1); }
    BARX;
    WAITL0; SCHED0;
    __builtin_amdgcn_s_setprio(1);
#pragma unroll
    for (int i = 0; i < 4; ++i)
#pragma unroll
      for (int j = 0; j < 4; ++j)
        acc[4 + i][j] = __builtin_amdgcn_mfma_f32_16x16x32_bf16(af[i], bfr[j], acc[4 + i][j], 0, 0, 0);
    __builtin_amdgcn_s_setprio(0);
    if (kt < NT - 3) { WAITV8; }
    else if (kt == NT - 3) { WAITV4; }
    else if (kt == NT - 2) { WAITV0; }
    BARX;
  }

  // ---- QKV epilogue over folded N = 6144 ----
#pragma unroll
  for (int i = 0; i < 8; ++i)
#pragma unroll
    for (int j = 0; j < 4; ++j) {
      int col = n0 + wn * 64 + j * 16 + ln15;
      int z = col >> 11;
      int c2 = col & 2047;
      int h = c2 >> 7, d = c2 & 127;
      int m = m0 + wm * 128 + i * 16 + lq * 4;
      int b = m >> 11, s = m & 2047;
      if (z == 2) {
        us4 pk;
#pragma unroll
        for (int r = 0; r < 4; ++r) pk[r] = f2bf(acc[i][j][r]);
        *(us4*)((unsigned short*)dv + (((size_t)b * NHc + h) * HDc + d) * SS + s) = pk;
      } else {
        unsigned short* D = (unsigned short*)(z ? dk : dq);
#pragma unroll
        for (int r = 0; r < 4; ++r)
          D[(((size_t)b * NHc + h) * SS + s + r) * HDc + d] = f2bf(acc[i][j][r]);
      }
    }
}

// ---------------------------------------------------------------------------
// 3b) Pipelined bf16 GEMM (R8 structure, proj only): BM=256 BN=128 BK=64,
//     3-deep LDS ring, distance-2 prefetch, counted vmcnt(6), 2 phases x
//     16-MFMA clusters.
// ---------------------------------------------------------------------------
template<int EPI, int NBX>
__global__ void __launch_bounds__(512, 2) gemm8(
    const unsigned short* __restrict__ A,
    const unsigned short* __restrict__ Bw,
    void* __restrict__ dq, void* __restrict__ dk, void* __restrict__ dv)
{
  __shared__ __align__(16) unsigned short Al[3][256 * 64];
  __shared__ __align__(16) unsigned short Bl[3][128 * 64];
  const int tid = threadIdx.x, lane = tid & 63, w = tid >> 6;
  const int wm = w >> 1, wn = w & 1;
  const int ln15 = lane & 15, lq = lane >> 4;

  const int xcd = blockIdx.x & 7, idx = blockIdx.x >> 3;
  const int by = xcd * 2 + idx / NBX, bx = idx % NBX;
  const int m0 = by * 256, n0 = bx * 128;

  const int srow = tid >> 3;                 // 0..63
  const int sc = (tid & 7) ^ (srow & 7);
  const unsigned short* asrc[4];
  const unsigned short* bsrc[2];
#pragma unroll
  for (int l = 0; l < 4; ++l) asrc[l] = A  + (size_t)(m0 + l * 64 + srow) * KC + sc * 8;
#pragma unroll
  for (int l = 0; l < 2; ++l) bsrc[l] = Bw + (size_t)(n0 + l * 64 + srow) * KC + sc * 8;

  const int x7 = ln15 & 7;
  const int slA0 = (lq ^ x7) * 8;
  const int slA1 = ((4 + lq) ^ x7) * 8;
  int rA[4], rB[4];
#pragma unroll
  for (int i = 0; i < 4; ++i) rA[i] = (wm * 64 + i * 16 + ln15) * 64;
#pragma unroll
  for (int j = 0; j < 4; ++j) rB[j] = (wn * 64 + j * 16 + ln15) * 64;

  constexpr int NT = KC / 64;   // 32
  auto stA = [&](int kt, int buf, int l) {
    gload_lds16(asrc[l] + (size_t)kt * 64, &Al[buf][(size_t)(l * 512 + w * 64) * 8]);
  };
  auto stB = [&](int kt, int buf, int l) {
    gload_lds16(bsrc[l] + (size_t)kt * 64, &Bl[buf][(size_t)(l * 512 + w * 64) * 8]);
  };

  stA(0, 0, 0); stA(0, 0, 1); stA(0, 0, 2); stA(0, 0, 3); stB(0, 0, 0); stB(0, 0, 1);
  stA(1, 1, 0); stA(1, 1, 1); stA(1, 1, 2); stA(1, 1, 3); stB(1, 1, 0); stB(1, 1, 1);
  WAITV6; BARX;

  f32x4 acc[4][4] = {};
  int cb = 0, nb = 2;
  for (int kt = 0; kt < NT; ++kt) {
    const unsigned short* Ac = &Al[cb][0];
    const unsigned short* Bc = &Bl[cb][0];
    const bool pf = (kt + 2 < NT);
    short8 a01[2][2], a23[2][2], bf[4][2];

#pragma unroll
    for (int i = 0; i < 2; ++i) {
      a01[i][0] = *(const short8*)&Ac[rA[i] + slA0];
      a01[i][1] = *(const short8*)&Ac[rA[i] + slA1];
    }
#pragma unroll
    for (int j = 0; j < 4; ++j) {
      bf[j][0] = *(const short8*)&Bc[rB[j] + slA0];
      bf[j][1] = *(const short8*)&Bc[rB[j] + slA1];
    }
    if (pf) { stA(kt + 2, nb, 0); stA(kt + 2, nb, 1); stA(kt + 2, nb, 2); }
    BARX;
    WAITL0; SCHED0;
    __builtin_amdgcn_s_setprio(1);
#pragma unroll
    for (int i = 0; i < 2; ++i)
#pragma unroll
      for (int j = 0; j < 4; ++j)
#pragma unroll
        for (int k = 0; k < 2; ++k)
          acc[i][j] = __builtin_amdgcn_mfma_f32_16x16x32_bf16(a01[i][k], bf[j][k], acc[i][j], 0, 0, 0);
    __builtin_amdgcn_s_setprio(0);
    BARX;

#pragma unroll
    for (int i = 0; i < 2; ++i) {
      a23[i][0] = *(const short8*)&Ac[rA[2 + i] + slA0];
      a23[i][1] = *(const short8*)&Ac[rA[2 + i] + slA1];
    }
    if (pf) { stA(kt + 2, nb, 3); stB(kt + 2, nb, 0); stB(kt + 2, nb, 1); }
    BARX;
    WAITL0; SCHED0;
    __builtin_amdgcn_s_setprio(1);
#pragma unroll
    for (int i = 0; i < 2; ++i)
#pragma unroll
      for (int j = 0; j < 4; ++j)
#pragma unroll
        for (int k = 0; k < 2; ++k)
          acc[2 + i][j] = __builtin_amdgcn_mfma_f32_16x16x32_bf16(a23[i][k], bf[j][k], acc[2 + i][j], 0, 0, 0);
    __builtin_amdgcn_s_setprio(0);
    if (kt < NT - 2) { WAITV6; }
    else if (kt == NT - 2) { WAITV0; }
    BARX;

    cb = (cb == 2) ? 0 : cb + 1;
    nb = (nb == 2) ? 0 : nb + 1;
  }

  if (EPI == 0) {
#pragma unroll
    for (int i = 0; i < 4; ++i)
#pragma unroll
      for (int j = 0; j < 4; ++j) {
        int colb = n0 + wn * 64 + j * 16;
        int z = colb >> 11;
        int c2 = (colb & 2047) + ln15;
        int h = c2 >> 7, d = c2 & 127;
        int m = m0 + wm * 64 + i * 16 + lq * 4;
        int b = m >> 11, s = m & 2047;
        if (z == 2) {
          us4 pk;
#pragma unroll
          for (int r = 0; r < 4; ++r) pk[r] = f2bf(acc[i][j][r]);
          *(us4*)((unsigned short*)dv + (((size_t)b * NHc + h) * HDc + d) * SS + s) = pk;
        } else {
          unsigned short* D = (unsigned short*)(z ? dk : dq);
#pragma unroll
          for (int r = 0; r < 4; ++r)
            D[(((size_t)b * NHc + h) * SS + s + r) * HDc + d] = f2bf(acc[i][j][r]);
        }
      }
  } else {
    float* O = (float*)dq;
#pragma unroll
    for (int i = 0; i < 4; ++i)
#pragma unroll
      for (int j = 0; j < 4; ++j) {
        int col = n0 + wn * 64 + j * 16 + ln15;
        int m = m0 + wm * 64 + i * 16 + lq * 4;
#pragma unroll
        for (int r = 0; r < 4; ++r)
          O[(size_t)(m + r) * HIDc + col] = acc[i][j][r];
      }
  }
}

// ---------------------------------------------------------------------------
// 4) in-place interleaved RoPE on Q and K
// ---------------------------------------------------------------------------
__global__ void __launch_bounds__(256) rope_kernel(
    unsigned int* __restrict__ Q, unsigned int* __restrict__ Kd,
    const float* __restrict__ cosT, const float* __restrict__ sinT)
{
  constexpr size_t NP = (size_t)BB * NHc * SS * 64;   // pairs per tensor
  size_t gid = (size_t)blockIdx.x * 256 + threadIdx.x;
  unsigned int* P = (gid < NP) ? Q : Kd;
  size_t r = (gid < NP) ? gid : gid - NP;
  int j  = (int)(r & 63);
  int s  = (int)((r >> 6) & (SS - 1));
  int fi = j & 31;
  float c  = cosT[s * 32 + fi];
  float sn = sinT[s * 32 + fi];
  unsigned v = P[r];
  float x1 = bf2f((unsigned short)(v & 0xffff));
  float x2 = bf2f((unsigned short)(v >> 16));
  float y1 = x1 * c - x2 * sn;
  float y2 = x1 * sn + x2 * c;
  P[r] = (unsigned)f2bf(y1) | ((unsigned)f2bf(y2) << 16);
}

// ---------------------------------------------------------------------------
// 5) causal flash attention v8 — 8-wave blocks, SIMD-complementary pairing
//    (R10 structure, unchanged).
// ---------------------------------------------------------------------------
__global__ void __launch_bounds__(512, 2) attn_kernel(
    const unsigned short* __restrict__ Qg,
    const unsigned short* __restrict__ Kg,
    const unsigned short* __restrict__ Vg,   // [b][h][d][s]
    unsigned short* __restrict__ Og)
{
  __shared__ __align__(16) unsigned short Klds[2][64 * 128];   // [kv][d] swizzled
  __shared__ __align__(16) unsigned short Vlds[2][128 * 64];   // [d][kv] swizzled
  __shared__ __align__(16) unsigned short Plds[8][32 * 64];    // per-wave [q][kv] swizzled
  const int tid = threadIdx.x, lane = tid & 63, w = tid >> 6;
  const int l31 = lane & 31, hi = lane >> 5;

  const int wg = blockIdx.x;
  const int xcd = wg & 7, idx = wg >> 3;
  const int bh = xcd + 8 * (idx & 3);
  const int tt = idx >> 2;                   // 0..7

  const int qtile = (w < 2) ? tt : (w < 4) ? (tt + 8) : (w < 6) ? (31 - tt) : (23 - tt);
  const int sub1 = w & 1;
  const int q0w = qtile * 64 + sub1 * 32;
  const int ntiles = 32 - tt;

  const size_t hbase = (size_t)bh * SS * HDc;
  const float CE = 1.44269504089f * 0.08838834764831845f;  // log2(e)/sqrt(128)
  const int b = bh >> 4, h = bh & 15;

  short8 qf[8];
#pragma unroll
  for (int ks = 0; ks < 8; ++ks)
    qf[ks] = *(const short8*)(Qg + hbase + (size_t)(q0w + l31) * HDc + ks * 16 + hi * 8);

  f32x16 accO[4];
#pragma unroll
  for (int db = 0; db < 4; ++db)
#pragma unroll
    for (int r = 0; r < 16; ++r) accO[db][r] = 0.f;
  float mr = -1e30f, lr = 0.f;

  auto stage = [&](int kvt, int buf) {
    const int kv0 = kvt * 64;
#pragma unroll
    for (int p = 0; p < 2; ++p) {
      int c = p * 512 + tid;                 // 0..1023
      int krow = c >> 4, ksl = c & 15;
      gload_lds16(Kg + hbase + (size_t)(kv0 + krow) * HDc + ((ksl ^ (krow & 7)) << 3),
                  (unsigned short*)&Klds[buf][0] + (size_t)c * 8);
      int vd = c >> 3, vsl = c & 7;
      gload_lds16(Vg + hbase + (size_t)vd * SS + kv0 + ((vsl ^ (vd & 7)) << 3),
                  (unsigned short*)&Vlds[buf][0] + (size_t)c * 8);
    }
  };

  stage(0, 0);
  __syncthreads();
  int cur = 0;
  for (int kvt = 0; kvt < ntiles; ++kvt) {
    if (kvt + 1 < ntiles) stage(kvt + 1, cur ^ 1);

    if (kvt <= qtile) {
      const bool diag = (kvt == qtile);
      const bool haveT1 = (!diag) || sub1;

      f32x16 s0, s1;
#pragma unroll
      for (int r = 0; r < 16; ++r) s0[r] = 0.f;
      __builtin_amdgcn_s_setprio(1);
#pragma unroll
      for (int ks = 0; ks < 8; ++ks) {
        int row = l31;
        short8 kf = *(const short8*)&Klds[cur][row * 128 + (((2 * ks + hi) ^ (row & 7)) << 3)];
        s0 = __builtin_amdgcn_mfma_f32_32x32x16_bf16(kf, qf[ks], s0, 0, 0, 0);
      }
      if (haveT1) {
#pragma unroll
        for (int r = 0; r < 16; ++r) s1[r] = 0.f;
#pragma unroll
        for (int ks = 0; ks < 8; ++ks) {
          int row = 32 + l31;
          short8 kf = *(const short8*)&Klds[cur][row * 128 + (((2 * ks + hi) ^ (row & 7)) << 3)];
          s1 = __builtin_amdgcn_mfma_f32_32x32x16_bf16(kf, qf[ks], s1, 0, 0, 0);
        }
      }
      __builtin_amdgcn_s_setprio(0);

      if (diag) {
        if (sub1) {
#pragma unroll
          for (int r = 0; r < 16; ++r)
            if (((r & 3) + 8 * (r >> 2) + 4 * hi) > l31) s1[r] = -1e30f;
        } else {
#pragma unroll
          for (int r = 0; r < 16; ++r)
            if (((r & 3) + 8 * (r >> 2) + 4 * hi) > l31) s0[r] = -1e30f;
        }
      }

      float pmax = s0[0];
#pragma unroll
      for (int r = 1; r < 16; ++r) pmax = fmaxf(pmax, s0[r]);
      if (haveT1) {
#pragma unroll
        for (int r = 0; r < 16; ++r) pmax = fmaxf(pmax, s1[r]);
      }
      pmax = fmaxf(pmax, __shfl_xor(pmax, 32));

      int grow = (CE * (pmax - mr) > 8.0f) ? 1 : 0;
      if (__any(grow)) {
        float mn = fmaxf(mr, pmax);
        float al = exp2f(CE * (mr - mn));
        mr = mn; lr *= al;
        float alr[16];
#pragma unroll
        for (int r = 0; r < 16; ++r)
          alr[r] = __shfl(al, (r & 3) + 8 * (r >> 2) + 4 * hi);
#pragma unroll
        for (int db = 0; db < 4; ++db)
#pragma unroll
          for (int r = 0; r < 16; ++r) accO[db][r] *= alr[r];
      }

      float psum = 0.f;
#pragma unroll
      for (int r = 0; r < 16; ++r) {
        float p = exp2f(CE * (s0[r] - mr));
        s0[r] = p; psum += p;
      }
      if (haveT1) {
#pragma unroll
        for (int r = 0; r < 16; ++r) {
          float p = exp2f(CE * (s1[r] - mr));
          s1[r] = p; psum += p;
        }
      }
      psum += __shfl_xor(psum, 32);
      lr += psum;

#pragma unroll
      for (int i = 0; i < 4; ++i) {
        uint2v pk;
        pk[0] = cvtpk_bf16(s0[4 * i], s0[4 * i + 1]);
        pk[1] = cvtpk_bf16(s0[4 * i + 2], s0[4 * i + 3]);
        int chunk = i ^ (l31 & 7);
        *(uint2v*)&Plds[w][l31 * 64 + chunk * 8 + hi * 4] = pk;
      }
      if (haveT1) {
#pragma unroll
        for (int i = 0; i < 4; ++i) {
          uint2v pk;
          pk[0] = cvtpk_bf16(s1[4 * i], s1[4 * i + 1]);
          pk[1] = cvtpk_bf16(s1[4 * i + 2], s1[4 * i + 3]);
          int chunk = (4 + i) ^ (l31 & 7);
          *(uint2v*)&Plds[w][l31 * 64 + chunk * 8 + hi * 4] = pk;
        }
      }

      short8 ap[4];
#pragma unroll
      for (int ks = 0; ks < 2; ++ks)
        ap[ks] = *(const short8*)&Plds[w][l31 * 64 + (((2 * ks + hi) ^ (l31 & 7)) << 3)];
      if (haveT1) {
#pragma unroll
        for (int ks = 2; ks < 4; ++ks)
          ap[ks] = *(const short8*)&Plds[w][l31 * 64 + (((2 * ks + hi) ^ (l31 & 7)) << 3)];
      }

      __builtin_amdgcn_s_setprio(1);
#pragma unroll
      for (int db = 0; db < 4; ++db) {
        int row = db * 32 + l31;
#pragma unroll
        for (int ks = 0; ks < 2; ++ks) {
          short8 vf = *(const short8*)&Vlds[cur][row * 64 + (((2 * ks + hi) ^ (row & 7)) << 3)];
          accO[db] = __builtin_amdgcn_mfma_f32_32x32x16_bf16(ap[ks], vf, accO[db], 0, 0, 0);
        }
      }
      if (haveT1) {
#pragma unroll
        for (int db = 0; db < 4; ++db) {
          int row = db * 32 + l31;
#pragma unroll
          for (int ks = 2; ks < 4; ++ks) {
            short8 vf = *(const short8*)&Vlds[cur][row * 64 + (((2 * ks + hi) ^ (row & 7)) << 3)];
            accO[db] = __builtin_amdgcn_mfma_f32_32x32x16_bf16(ap[ks], vf, accO[db], 0, 0, 0);
          }
        }
      }
      __builtin_amdgcn_s_setprio(0);
    }

    __syncthreads();
    cur ^= 1;
  }

  float il = 1.0f / lr;
  float ilr[16];
#pragma unroll
  for (int r = 0; r < 16; ++r)
    ilr[r] = __shfl(il, (r & 3) + 8 * (r >> 2) + 4 * hi);
#pragma unroll
  for (int db = 0; db < 4; ++db)
#pragma unroll
    for (int r = 0; r < 16; ++r) {
      int q = q0w + (r & 3) + 8 * (r >> 2) + 4 * hi;
      int d = db * 32 + l31;
      Og[((size_t)b * SS + q) * HIDc + h * HDc + d] = f2bf(accO[db][r] * ilr[r]);
    }
}

// ---------------------------------------------------------------------------
extern "C" void kernel_launch(void* const* d_in, const int* in_sizes, int n_in,
                              void* d_out, int out_size, void* d_ws, size_t ws_size,
                              hipStream_t stream)
{
  if (ws_size < WS_NEED) return;

  const float* H  = (const float*)d_in[0];
  const float* Wq = (const float*)d_in[1];
  const float* Wk = (const float*)d_in[2];
  const float* Wv = (const float*)d_in[3];
  const float* Wo = (const float*)d_in[4];
  char* ws = (char*)d_ws;
  unsigned short* HB = (unsigned short*)(ws + OFF_HB);
  unsigned short* WB = (unsigned short*)(ws + OFF_WB);
  unsigned short* Qb = (unsigned short*)(ws + OFF_Q);
  unsigned short* Kb = (unsigned short*)(ws + OFF_K);
  unsigned short* Vb = (unsigned short*)(ws + OFF_V);
  unsigned short* AT = (unsigned short*)(ws + OFF_ATT);
  float* cosT = (float*)(ws + OFF_COS);
  float* sinT = (float*)(ws + OFF_SIN);

  cvt_kernel<<<12288, 256, 0, stream>>>(H, Wq, Wk, Wv, Wo, HB);
  rope_tab_kernel<<<256, 256, 0, stream>>>(cosT, sinT);
  // QKV: folded N = 6144, BM=BN=256 -> grid 8 XCD * 2 by * 24 bx = 384
  gemmQKV<24><<<384, 512, 0, stream>>>(HB, WB, Qb, Kb, Vb);
  rope_kernel<<<32768, 256, 0, stream>>>((unsigned*)Qb, (unsigned*)Kb, cosT, sinT);
  attn_kernel<<<256, 512, 0, stream>>>(Qb, Kb, Vb, AT);
  // proj: N = 2048 -> grid 8 * 2 * 16 = 256
  gemm8<1, 16><<<256, 512, 0, stream>>>(AT, WB + (size_t)3 * HIDc * KC,
                                        d_out, nullptr, nullptr);
}

// Round 12
// 262.545 us; speedup vs baseline: 1.1138x; 1.1138x over previous
//
#include <hip/hip_runtime.h>
#include <math.h>

typedef __attribute__((ext_vector_type(8))) short short8;
typedef __attribute__((ext_vector_type(4))) float f32x4;
typedef __attribute__((ext_vector_type(16))) float f32x16;
typedef __attribute__((ext_vector_type(4))) float fvec4;
typedef __attribute__((ext_vector_type(4))) unsigned short us4;
typedef __attribute__((ext_vector_type(2))) unsigned int uint2v;

#define DI __device__ __forceinline__
#define BARX asm volatile("s_barrier" ::: "memory")
#define WAITV6 asm volatile("s_waitcnt vmcnt(6)" ::: "memory")
#define WAITV0 asm volatile("s_waitcnt vmcnt(0)" ::: "memory")
#define WAITL0 asm volatile("s_waitcnt lgkmcnt(0)" ::: "memory")
#define SCHED0 __builtin_amdgcn_sched_barrier(0)

constexpr int BB = 2, SS = 2048, HIDc = 2048, NHc = 16, HDc = 128;
constexpr int MT = BB * SS;     // 4096 tokens
constexpr int KC = HIDc;        // 2048 inner dim

// ---- workspace layout (bytes) ----
constexpr size_t OFF_HB  = 0;                                      // H bf16   [4096][2048]
constexpr size_t OFF_WB  = OFF_HB + (size_t)MT * KC * 2;           // W bf16   4x[2048][2048]
constexpr size_t OFF_Q   = OFF_WB + (size_t)4 * HIDc * KC * 2;     // Q bf16   [b][h][s][d]
constexpr size_t OFF_K   = OFF_Q  + (size_t)BB * NHc * SS * HDc * 2;
constexpr size_t OFF_V   = OFF_K  + (size_t)BB * NHc * SS * HDc * 2; // V bf16 [b][h][d][s]
constexpr size_t OFF_ATT = OFF_V  + (size_t)BB * NHc * SS * HDc * 2; // attn bf16 [b*s][hid]
constexpr size_t OFF_COS = OFF_ATT + (size_t)MT * HIDc * 2;
constexpr size_t OFF_SIN = OFF_COS + (size_t)SS * 32 * 4;
constexpr size_t WS_NEED = OFF_SIN + (size_t)SS * 32 * 4;          // ~118 MB

DI float bf2f(unsigned short u) { union { unsigned u; float f; } v; v.u = (unsigned)u << 16; return v.f; }
DI unsigned short f2bf(float f) {
  union { float f; unsigned u; } v; v.f = f;
  unsigned r = v.u + 0x7fffu + ((v.u >> 16) & 1u);
  return (unsigned short)(r >> 16);
}

DI void gload_lds16(const void* g, void* l) {
  __builtin_amdgcn_global_load_lds((const __attribute__((address_space(1))) void*)g,
                                   (__attribute__((address_space(3))) void*)l, 16, 0, 0);
}

DI unsigned cvtpk_bf16(float lo, float hi_) {
  unsigned r;
  asm("v_cvt_pk_bf16_f32 %0, %1, %2" : "=v"(r) : "v"(lo), "v"(hi_));
  return r;
}

// ---------------------------------------------------------------------------
// 1) fp32 -> bf16 convert of H and the 4 weights into one contiguous region
// ---------------------------------------------------------------------------
__global__ void __launch_bounds__(256) cvt_kernel(
    const float* __restrict__ H,  const float* __restrict__ W0,
    const float* __restrict__ W1, const float* __restrict__ W2,
    const float* __restrict__ W3, unsigned short* __restrict__ dst)
{
  constexpr size_t HN = (size_t)MT * KC;      // 8388608
  constexpr size_t WN = (size_t)HIDc * KC;    // 4194304 = 2^22
  size_t e0 = ((size_t)blockIdx.x * 256 + threadIdx.x) * 8;
  const float* src; size_t off;
  if (e0 < HN) { src = H; off = e0; }
  else {
    size_t t = e0 - HN; int a = (int)(t >> 22);
    src = (a == 0) ? W0 : (a == 1) ? W1 : (a == 2) ? W2 : W3;
    off = t & (WN - 1);
  }
  fvec4 v0 = *(const fvec4*)(src + off);
  fvec4 v1 = *(const fvec4*)(src + off + 4);
  short8 o;
  o[0] = (short)f2bf(v0[0]); o[1] = (short)f2bf(v0[1]);
  o[2] = (short)f2bf(v0[2]); o[3] = (short)f2bf(v0[3]);
  o[4] = (short)f2bf(v1[0]); o[5] = (short)f2bf(v1[1]);
  o[6] = (short)f2bf(v1[2]); o[7] = (short)f2bf(v1[3]);
  *(short8*)(dst + e0) = o;
}

// ---------------------------------------------------------------------------
// 2) RoPE tables: theta(t, fi) = t * 10000^(-fi/32), fi = pair-idx mod 32
// ---------------------------------------------------------------------------
__global__ void __launch_bounds__(256) rope_tab_kernel(float* __restrict__ cosT,
                                                       float* __restrict__ sinT)
{
  int idx = blockIdx.x * 256 + threadIdx.x;   // S*32 = 65536
  int t = idx >> 5, fi = idx & 31;
  float inv = powf(10000.0f, -(float)fi * (1.0f / 32.0f));
  float ang = (float)t * inv;
  cosT[idx] = cosf(ang);
  sinT[idx] = sinf(ang);
}

// ---------------------------------------------------------------------------
// 3) Pipelined bf16 GEMM (R8/R10 structure): BM=256 BN=128 BK=64,
//    3-deep LDS ring, distance-2 prefetch, counted vmcnt(6), 2 phases x
//    16-MFMA clusters. Swizzle chunk^(row&7), both sides (conflict-free).
//    EPI 0: folded-N=6144 QKV epilogue WITH FUSED RoPE on Q,K (z<2):
//      pair partner d^1 lives in lane^1 (shfl_xor -> DPP), cos/sin from
//      precomputed tables. V (z=2) unrotated, stored [b][h][d][s].
//    EPI 1: fp32 row-major out (proj).
// ---------------------------------------------------------------------------
template<int EPI, int NBX>
__global__ void __launch_bounds__(512, 2) gemm8(
    const unsigned short* __restrict__ A,
    const unsigned short* __restrict__ Bw,
    void* __restrict__ dq, void* __restrict__ dk, void* __restrict__ dv,
    const float* __restrict__ cosT, const float* __restrict__ sinT)
{
  __shared__ __align__(16) unsigned short Al[3][256 * 64];
  __shared__ __align__(16) unsigned short Bl[3][128 * 64];
  const int tid = threadIdx.x, lane = tid & 63, w = tid >> 6;
  const int wm = w >> 1, wn = w & 1;
  const int ln15 = lane & 15, lq = lane >> 4;

  const int xcd = blockIdx.x & 7, idx = blockIdx.x >> 3;
  const int by = xcd * 2 + idx / NBX, bx = idx % NBX;
  const int m0 = by * 256, n0 = bx * 128;

  const int srow = tid >> 3;                 // 0..63
  const int sc = (tid & 7) ^ (srow & 7);
  const unsigned short* asrc[4];
  const unsigned short* bsrc[2];
#pragma unroll
  for (int l = 0; l < 4; ++l) asrc[l] = A  + (size_t)(m0 + l * 64 + srow) * KC + sc * 8;
#pragma unroll
  for (int l = 0; l < 2; ++l) bsrc[l] = Bw + (size_t)(n0 + l * 64 + srow) * KC + sc * 8;

  const int x7 = ln15 & 7;
  const int slA0 = (lq ^ x7) * 8;
  const int slA1 = ((4 + lq) ^ x7) * 8;
  int rA[4], rB[4];
#pragma unroll
  for (int i = 0; i < 4; ++i) rA[i] = (wm * 64 + i * 16 + ln15) * 64;
#pragma unroll
  for (int j = 0; j < 4; ++j) rB[j] = (wn * 64 + j * 16 + ln15) * 64;

  constexpr int NT = KC / 64;   // 32
  auto stA = [&](int kt, int buf, int l) {
    gload_lds16(asrc[l] + (size_t)kt * 64, &Al[buf][(size_t)(l * 512 + w * 64) * 8]);
  };
  auto stB = [&](int kt, int buf, int l) {
    gload_lds16(bsrc[l] + (size_t)kt * 64, &Bl[buf][(size_t)(l * 512 + w * 64) * 8]);
  };

  stA(0, 0, 0); stA(0, 0, 1); stA(0, 0, 2); stA(0, 0, 3); stB(0, 0, 0); stB(0, 0, 1);
  stA(1, 1, 0); stA(1, 1, 1); stA(1, 1, 2); stA(1, 1, 3); stB(1, 1, 0); stB(1, 1, 1);
  WAITV6; BARX;

  f32x4 acc[4][4] = {};
  int cb = 0, nb = 2;
  for (int kt = 0; kt < NT; ++kt) {
    const unsigned short* Ac = &Al[cb][0];
    const unsigned short* Bc = &Bl[cb][0];
    const bool pf = (kt + 2 < NT);
    short8 a01[2][2], a23[2][2], bf[4][2];

#pragma unroll
    for (int i = 0; i < 2; ++i) {
      a01[i][0] = *(const short8*)&Ac[rA[i] + slA0];
      a01[i][1] = *(const short8*)&Ac[rA[i] + slA1];
    }
#pragma unroll
    for (int j = 0; j < 4; ++j) {
      bf[j][0] = *(const short8*)&Bc[rB[j] + slA0];
      bf[j][1] = *(const short8*)&Bc[rB[j] + slA1];
    }
    if (pf) { stA(kt + 2, nb, 0); stA(kt + 2, nb, 1); stA(kt + 2, nb, 2); }
    BARX;
    WAITL0; SCHED0;
    __builtin_amdgcn_s_setprio(1);
#pragma unroll
    for (int i = 0; i < 2; ++i)
#pragma unroll
      for (int j = 0; j < 4; ++j)
#pragma unroll
        for (int k = 0; k < 2; ++k)
          acc[i][j] = __builtin_amdgcn_mfma_f32_16x16x32_bf16(a01[i][k], bf[j][k], acc[i][j], 0, 0, 0);
    __builtin_amdgcn_s_setprio(0);
    BARX;

#pragma unroll
    for (int i = 0; i < 2; ++i) {
      a23[i][0] = *(const short8*)&Ac[rA[2 + i] + slA0];
      a23[i][1] = *(const short8*)&Ac[rA[2 + i] + slA1];
    }
    if (pf) { stA(kt + 2, nb, 3); stB(kt + 2, nb, 0); stB(kt + 2, nb, 1); }
    BARX;
    WAITL0; SCHED0;
    __builtin_amdgcn_s_setprio(1);
#pragma unroll
    for (int i = 0; i < 2; ++i)
#pragma unroll
      for (int j = 0; j < 4; ++j)
#pragma unroll
        for (int k = 0; k < 2; ++k)
          acc[2 + i][j] = __builtin_amdgcn_mfma_f32_16x16x32_bf16(a23[i][k], bf[j][k], acc[2 + i][j], 0, 0, 0);
    __builtin_amdgcn_s_setprio(0);
    if (kt < NT - 2) { WAITV6; }
    else if (kt == NT - 2) { WAITV0; }
    BARX;

    cb = (cb == 2) ? 0 : cb + 1;
    nb = (nb == 2) ? 0 : nb + 1;
  }

  if (EPI == 0) {
#pragma unroll
    for (int i = 0; i < 4; ++i)
#pragma unroll
      for (int j = 0; j < 4; ++j) {
        int colb = n0 + wn * 64 + j * 16;         // + ln15
        int z = colb >> 11;
        int c2 = (colb & 2047) + ln15;
        int h = c2 >> 7, d = c2 & 127;
        int m = m0 + wm * 64 + i * 16 + lq * 4;   // + rr
        int b = m >> 11, s = m & 2047;
        if (z == 2) {
          us4 pk;
#pragma unroll
          for (int r = 0; r < 4; ++r) pk[r] = f2bf(acc[i][j][r]);
          *(us4*)((unsigned short*)dv + (((size_t)b * NHc + h) * HDc + d) * SS + s) = pk;
        } else {
          // fused RoPE: partner dim d^1 lives in lane^1 (same i,j,r)
          unsigned short* D = (unsigned short*)(z ? dk : dq);
          const int fi = (d >> 1) & 31;
          const bool odd = (d & 1) != 0;
#pragma unroll
          for (int r = 0; r < 4; ++r) {
            float v = acc[i][j][r];
            float p = __shfl_xor(v, 1);
            float cs = cosT[(size_t)(s + r) * 32 + fi];
            float sn = sinT[(size_t)(s + r) * 32 + fi];
            float y = odd ? (p * sn + v * cs) : (v * cs - p * sn);
            D[(((size_t)b * NHc + h) * SS + s + r) * HDc + d] = f2bf(y);
          }
        }
      }
  } else {
    float* O = (float*)dq;
#pragma unroll
    for (int i = 0; i < 4; ++i)
#pragma unroll
      for (int j = 0; j < 4; ++j) {
        int col = n0 + wn * 64 + j * 16 + ln15;
        int m = m0 + wm * 64 + i * 16 + lq * 4;
#pragma unroll
        for (int r = 0; r < 4; ++r)
          O[(size_t)(m + r) * HIDc + col] = acc[i][j][r];
      }
  }
}

// ---------------------------------------------------------------------------
// 4) causal flash attention v8 — 8-wave blocks, SIMD-complementary pairing
//    (R10 structure, unchanged).
// ---------------------------------------------------------------------------
__global__ void __launch_bounds__(512, 2) attn_kernel(
    const unsigned short* __restrict__ Qg,
    const unsigned short* __restrict__ Kg,
    const unsigned short* __restrict__ Vg,   // [b][h][d][s]
    unsigned short* __restrict__ Og)
{
  __shared__ __align__(16) unsigned short Klds[2][64 * 128];   // [kv][d] swizzled
  __shared__ __align__(16) unsigned short Vlds[2][128 * 64];   // [d][kv] swizzled
  __shared__ __align__(16) unsigned short Plds[8][32 * 64];    // per-wave [q][kv] swizzled
  const int tid = threadIdx.x, lane = tid & 63, w = tid >> 6;
  const int l31 = lane & 31, hi = lane >> 5;

  const int wg = blockIdx.x;
  const int xcd = wg & 7, idx = wg >> 3;
  const int bh = xcd + 8 * (idx & 3);
  const int tt = idx >> 2;                   // 0..7

  const int qtile = (w < 2) ? tt : (w < 4) ? (tt + 8) : (w < 6) ? (31 - tt) : (23 - tt);
  const int sub1 = w & 1;
  const int q0w = qtile * 64 + sub1 * 32;
  const int ntiles = 32 - tt;

  const size_t hbase = (size_t)bh * SS * HDc;
  const float CE = 1.44269504089f * 0.08838834764831845f;  // log2(e)/sqrt(128)
  const int b = bh >> 4, h = bh & 15;

  short8 qf[8];
#pragma unroll
  for (int ks = 0; ks < 8; ++ks)
    qf[ks] = *(const short8*)(Qg + hbase + (size_t)(q0w + l31) * HDc + ks * 16 + hi * 8);

  f32x16 accO[4];
#pragma unroll
  for (int db = 0; db < 4; ++db)
#pragma unroll
    for (int r = 0; r < 16; ++r) accO[db][r] = 0.f;
  float mr = -1e30f, lr = 0.f;

  auto stage = [&](int kvt, int buf) {
    const int kv0 = kvt * 64;
#pragma unroll
    for (int p = 0; p < 2; ++p) {
      int c = p * 512 + tid;                 // 0..1023
      int krow = c >> 4, ksl = c & 15;
      gload_lds16(Kg + hbase + (size_t)(kv0 + krow) * HDc + ((ksl ^ (krow & 7)) << 3),
                  (unsigned short*)&Klds[buf][0] + (size_t)c * 8);
      int vd = c >> 3, vsl = c & 7;
      gload_lds16(Vg + hbase + (size_t)vd * SS + kv0 + ((vsl ^ (vd & 7)) << 3),
                  (unsigned short*)&Vlds[buf][0] + (size_t)c * 8);
    }
  };

  stage(0, 0);
  __syncthreads();
  int cur = 0;
  for (int kvt = 0; kvt < ntiles; ++kvt) {
    if (kvt + 1 < ntiles) stage(kvt + 1, cur ^ 1);

    if (kvt <= qtile) {
      const bool diag = (kvt == qtile);
      const bool haveT1 = (!diag) || sub1;

      f32x16 s0, s1;
#pragma unroll
      for (int r = 0; r < 16; ++r) s0[r] = 0.f;
      __builtin_amdgcn_s_setprio(1);
#pragma unroll
      for (int ks = 0; ks < 8; ++ks) {
        int row = l31;
        short8 kf = *(const short8*)&Klds[cur][row * 128 + (((2 * ks + hi) ^ (row & 7)) << 3)];
        s0 = __builtin_amdgcn_mfma_f32_32x32x16_bf16(kf, qf[ks], s0, 0, 0, 0);
      }
      if (haveT1) {
#pragma unroll
        for (int r = 0; r < 16; ++r) s1[r] = 0.f;
#pragma unroll
        for (int ks = 0; ks < 8; ++ks) {
          int row = 32 + l31;
          short8 kf = *(const short8*)&Klds[cur][row * 128 + (((2 * ks + hi) ^ (row & 7)) << 3)];
          s1 = __builtin_amdgcn_mfma_f32_32x32x16_bf16(kf, qf[ks], s1, 0, 0, 0);
        }
      }
      __builtin_amdgcn_s_setprio(0);

      if (diag) {
        if (sub1) {
#pragma unroll
          for (int r = 0; r < 16; ++r)
            if (((r & 3) + 8 * (r >> 2) + 4 * hi) > l31) s1[r] = -1e30f;
        } else {
#pragma unroll
          for (int r = 0; r < 16; ++r)
            if (((r & 3) + 8 * (r >> 2) + 4 * hi) > l31) s0[r] = -1e30f;
        }
      }

      float pmax = s0[0];
#pragma unroll
      for (int r = 1; r < 16; ++r) pmax = fmaxf(pmax, s0[r]);
      if (haveT1) {
#pragma unroll
        for (int r = 0; r < 16; ++r) pmax = fmaxf(pmax, s1[r]);
      }
      pmax = fmaxf(pmax, __shfl_xor(pmax, 32));

      int grow = (CE * (pmax - mr) > 8.0f) ? 1 : 0;
      if (__any(grow)) {
        float mn = fmaxf(mr, pmax);
        float al = exp2f(CE * (mr - mn));
        mr = mn; lr *= al;
        float alr[16];
#pragma unroll
        for (int r = 0; r < 16; ++r)
          alr[r] = __shfl(al, (r & 3) + 8 * (r >> 2) + 4 * hi);
#pragma unroll
        for (int db = 0; db < 4; ++db)
#pragma unroll
          for (int r = 0; r < 16; ++r) accO[db][r] *= alr[r];
      }

      float psum = 0.f;
#pragma unroll
      for (int r = 0; r < 16; ++r) {
        float p = exp2f(CE * (s0[r] - mr));
        s0[r] = p; psum += p;
      }
      if (haveT1) {
#pragma unroll
        for (int r = 0; r < 16; ++r) {
          float p = exp2f(CE * (s1[r] - mr));
          s1[r] = p; psum += p;
        }
      }
      psum += __shfl_xor(psum, 32);
      lr += psum;

#pragma unroll
      for (int i = 0; i < 4; ++i) {
        uint2v pk;
        pk[0] = cvtpk_bf16(s0[4 * i], s0[4 * i + 1]);
        pk[1] = cvtpk_bf16(s0[4 * i + 2], s0[4 * i + 3]);
        int chunk = i ^ (l31 & 7);
        *(uint2v*)&Plds[w][l31 * 64 + chunk * 8 + hi * 4] = pk;
      }
      if (haveT1) {
#pragma unroll
        for (int i = 0; i < 4; ++i) {
          uint2v pk;
          pk[0] = cvtpk_bf16(s1[4 * i], s1[4 * i + 1]);
          pk[1] = cvtpk_bf16(s1[4 * i + 2], s1[4 * i + 3]);
          int chunk = (4 + i) ^ (l31 & 7);
          *(uint2v*)&Plds[w][l31 * 64 + chunk * 8 + hi * 4] = pk;
        }
      }

      short8 ap[4];
#pragma unroll
      for (int ks = 0; ks < 2; ++ks)
        ap[ks] = *(const short8*)&Plds[w][l31 * 64 + (((2 * ks + hi) ^ (l31 & 7)) << 3)];
      if (haveT1) {
#pragma unroll
        for (int ks = 2; ks < 4; ++ks)
          ap[ks] = *(const short8*)&Plds[w][l31 * 64 + (((2 * ks + hi) ^ (l31 & 7)) << 3)];
      }

      __builtin_amdgcn_s_setprio(1);
#pragma unroll
      for (int db = 0; db < 4; ++db) {
        int row = db * 32 + l31;
#pragma unroll
        for (int ks = 0; ks < 2; ++ks) {
          short8 vf = *(const short8*)&Vlds[cur][row * 64 + (((2 * ks + hi) ^ (row & 7)) << 3)];
          accO[db] = __builtin_amdgcn_mfma_f32_32x32x16_bf16(ap[ks], vf, accO[db], 0, 0, 0);
        }
      }
      if (haveT1) {
#pragma unroll
        for (int db = 0; db < 4; ++db) {
          int row = db * 32 + l31;
#pragma unroll
          for (int ks = 2; ks < 4; ++ks) {
            short8 vf = *(const short8*)&Vlds[cur][row * 64 + (((2 * ks + hi) ^ (row & 7)) << 3)];
            accO[db] = __builtin_amdgcn_mfma_f32_32x32x16_bf16(ap[ks], vf, accO[db], 0, 0, 0);
          }
        }
      }
      __builtin_amdgcn_s_setprio(0);
    }

    __syncthreads();
    cur ^= 1;
  }

  float il = 1.0f / lr;
  float ilr[16];
#pragma unroll
  for (int r = 0; r < 16; ++r)
    ilr[r] = __shfl(il, (r & 3) + 8 * (r >> 2) + 4 * hi);
#pragma unroll
  for (int db = 0; db < 4; ++db)
#pragma unroll
    for (int r = 0; r < 16; ++r) {
      int q = q0w + (r & 3) + 8 * (r >> 2) + 4 * hi;
      int d = db * 32 + l31;
      Og[((size_t)b * SS + q) * HIDc + h * HDc + d] = f2bf(accO[db][r] * ilr[r]);
    }
}

// ---------------------------------------------------------------------------
extern "C" void kernel_launch(void* const* d_in, const int* in_sizes, int n_in,
                              void* d_out, int out_size, void* d_ws, size_t ws_size,
                              hipStream_t stream)
{
  if (ws_size < WS_NEED) return;

  const float* H  = (const float*)d_in[0];
  const float* Wq = (const float*)d_in[1];
  const float* Wk = (const float*)d_in[2];
  const float* Wv = (const float*)d_in[3];
  const float* Wo = (const float*)d_in[4];
  char* ws = (char*)d_ws;
  unsigned short* HB = (unsigned short*)(ws + OFF_HB);
  unsigned short* WB = (unsigned short*)(ws + OFF_WB);
  unsigned short* Qb = (unsigned short*)(ws + OFF_Q);
  unsigned short* Kb = (unsigned short*)(ws + OFF_K);
  unsigned short* Vb = (unsigned short*)(ws + OFF_V);
  unsigned short* AT = (unsigned short*)(ws + OFF_ATT);
  float* cosT = (float*)(ws + OFF_COS);
  float* sinT = (float*)(ws + OFF_SIN);

  cvt_kernel<<<12288, 256, 0, stream>>>(H, Wq, Wk, Wv, Wo, HB);
  rope_tab_kernel<<<256, 256, 0, stream>>>(cosT, sinT);
  // QKV: folded N = 6144, fused RoPE epilogue -> grid 8 XCD * 2 by * 48 bx = 768
  gemm8<0, 48><<<768, 512, 0, stream>>>(HB, WB, Qb, Kb, Vb, cosT, sinT);
  attn_kernel<<<256, 512, 0, stream>>>(Qb, Kb, Vb, AT);
  // proj: N = 2048 -> grid 8 * 2 * 16 = 256
  gemm8<1, 16><<<256, 512, 0, stream>>>(AT, WB + (size_t)3 * HIDc * KC,
                                        d_out, nullptr, nullptr, nullptr, nullptr);
}

// Round 13
// 261.622 us; speedup vs baseline: 1.1177x; 1.0035x over previous
//
#include <hip/hip_runtime.h>
#include <math.h>

typedef __attribute__((ext_vector_type(8))) short short8;
typedef __attribute__((ext_vector_type(4))) float f32x4;
typedef __attribute__((ext_vector_type(16))) float f32x16;
typedef __attribute__((ext_vector_type(4))) float fvec4;
typedef __attribute__((ext_vector_type(4))) unsigned short us4;
typedef __attribute__((ext_vector_type(2))) unsigned int uint2v;

#define DI __device__ __forceinline__
#define BARX asm volatile("s_barrier" ::: "memory")
#define WAITV6 asm volatile("s_waitcnt vmcnt(6)" ::: "memory")
#define WAITV4 asm volatile("s_waitcnt vmcnt(4)" ::: "memory")
#define WAITV0 asm volatile("s_waitcnt vmcnt(0)" ::: "memory")
#define WAITL0 asm volatile("s_waitcnt lgkmcnt(0)" ::: "memory")
#define SCHED0 __builtin_amdgcn_sched_barrier(0)

constexpr int BB = 2, SS = 2048, HIDc = 2048, NHc = 16, HDc = 128;
constexpr int MT = BB * SS;     // 4096 tokens
constexpr int KC = HIDc;        // 2048 inner dim

// ---- workspace layout (bytes) ----
constexpr size_t OFF_HB  = 0;                                      // H bf16   [4096][2048]
constexpr size_t OFF_WB  = OFF_HB + (size_t)MT * KC * 2;           // W bf16   4x[2048][2048]
constexpr size_t OFF_Q   = OFF_WB + (size_t)4 * HIDc * KC * 2;     // Q bf16   [b][h][s][d]
constexpr size_t OFF_K   = OFF_Q  + (size_t)BB * NHc * SS * HDc * 2;
constexpr size_t OFF_V   = OFF_K  + (size_t)BB * NHc * SS * HDc * 2; // V bf16 [b][h][d][s]
constexpr size_t OFF_ATT = OFF_V  + (size_t)BB * NHc * SS * HDc * 2; // attn bf16 [b*s][hid]
constexpr size_t OFF_COS = OFF_ATT + (size_t)MT * HIDc * 2;
constexpr size_t OFF_SIN = OFF_COS + (size_t)SS * 32 * 4;
constexpr size_t WS_NEED = OFF_SIN + (size_t)SS * 32 * 4;          // ~118 MB

DI float bf2f(unsigned short u) { union { unsigned u; float f; } v; v.u = (unsigned)u << 16; return v.f; }
DI unsigned short f2bf(float f) {
  union { float f; unsigned u; } v; v.f = f;
  unsigned r = v.u + 0x7fffu + ((v.u >> 16) & 1u);
  return (unsigned short)(r >> 16);
}

DI void gload_lds16(const void* g, void* l) {
  __builtin_amdgcn_global_load_lds((const __attribute__((address_space(1))) void*)g,
                                   (__attribute__((address_space(3))) void*)l, 16, 0, 0);
}

DI unsigned cvtpk_bf16(float lo, float hi_) {
  unsigned r;
  asm("v_cvt_pk_bf16_f32 %0, %1, %2" : "=v"(r) : "v"(lo), "v"(hi_));
  return r;
}

// ---------------------------------------------------------------------------
// 1) fp32 -> bf16 convert of H and the 4 weights + RoPE tables (fused tail)
// ---------------------------------------------------------------------------
__global__ void __launch_bounds__(256) cvt_kernel(
    const float* __restrict__ H,  const float* __restrict__ W0,
    const float* __restrict__ W1, const float* __restrict__ W2,
    const float* __restrict__ W3, unsigned short* __restrict__ dst,
    float* __restrict__ cosT, float* __restrict__ sinT)
{
  constexpr size_t HN = (size_t)MT * KC;      // 8388608
  constexpr size_t WN = (size_t)HIDc * KC;    // 4194304 = 2^22
  if (blockIdx.x >= 12288) {                  // RoPE-table tail blocks
    int idx = (blockIdx.x - 12288) * 256 + threadIdx.x;   // S*32 = 65536
    int t = idx >> 5, fi = idx & 31;
    float inv = powf(10000.0f, -(float)fi * (1.0f / 32.0f));
    float ang = (float)t * inv;
    cosT[idx] = cosf(ang);
    sinT[idx] = sinf(ang);
    return;
  }
  size_t e0 = ((size_t)blockIdx.x * 256 + threadIdx.x) * 8;
  const float* src; size_t off;
  if (e0 < HN) { src = H; off = e0; }
  else {
    size_t t = e0 - HN; int a = (int)(t >> 22);
    src = (a == 0) ? W0 : (a == 1) ? W1 : (a == 2) ? W2 : W3;
    off = t & (WN - 1);
  }
  fvec4 v0 = *(const fvec4*)(src + off);
  fvec4 v1 = *(const fvec4*)(src + off + 4);
  short8 o;
  o[0] = (short)f2bf(v0[0]); o[1] = (short)f2bf(v0[1]);
  o[2] = (short)f2bf(v0[2]); o[3] = (short)f2bf(v0[3]);
  o[4] = (short)f2bf(v1[0]); o[5] = (short)f2bf(v1[1]);
  o[6] = (short)f2bf(v1[2]); o[7] = (short)f2bf(v1[3]);
  *(short8*)(dst + e0) = o;
}

// ---------------------------------------------------------------------------
// 2) Pipelined bf16 GEMM (R8/R12 structure): BM=256 BN=128 BK=64,
//    3-deep LDS ring, distance-2 prefetch, counted vmcnt(6), 2 phases x
//    16-MFMA clusters. Swizzle chunk^(row&7), both sides (conflict-free).
//    EPI 0: folded-N=6144 QKV epilogue WITH FUSED RoPE on Q,K (z<2).
//    EPI 1: fp32 row-major out (proj).
// ---------------------------------------------------------------------------
template<int EPI, int NBX>
__global__ void __launch_bounds__(512, 2) gemm8(
    const unsigned short* __restrict__ A,
    const unsigned short* __restrict__ Bw,
    void* __restrict__ dq, void* __restrict__ dk, void* __restrict__ dv,
    const float* __restrict__ cosT, const float* __restrict__ sinT)
{
  __shared__ __align__(16) unsigned short Al[3][256 * 64];
  __shared__ __align__(16) unsigned short Bl[3][128 * 64];
  const int tid = threadIdx.x, lane = tid & 63, w = tid >> 6;
  const int wm = w >> 1, wn = w & 1;
  const int ln15 = lane & 15, lq = lane >> 4;

  const int xcd = blockIdx.x & 7, idx = blockIdx.x >> 3;
  const int by = xcd * 2 + idx / NBX, bx = idx % NBX;
  const int m0 = by * 256, n0 = bx * 128;

  const int srow = tid >> 3;                 // 0..63
  const int sc = (tid & 7) ^ (srow & 7);
  const unsigned short* asrc[4];
  const unsigned short* bsrc[2];
#pragma unroll
  for (int l = 0; l < 4; ++l) asrc[l] = A  + (size_t)(m0 + l * 64 + srow) * KC + sc * 8;
#pragma unroll
  for (int l = 0; l < 2; ++l) bsrc[l] = Bw + (size_t)(n0 + l * 64 + srow) * KC + sc * 8;

  const int x7 = ln15 & 7;
  const int slA0 = (lq ^ x7) * 8;
  const int slA1 = ((4 + lq) ^ x7) * 8;
  int rA[4], rB[4];
#pragma unroll
  for (int i = 0; i < 4; ++i) rA[i] = (wm * 64 + i * 16 + ln15) * 64;
#pragma unroll
  for (int j = 0; j < 4; ++j) rB[j] = (wn * 64 + j * 16 + ln15) * 64;

  constexpr int NT = KC / 64;   // 32
  auto stA = [&](int kt, int buf, int l) {
    gload_lds16(asrc[l] + (size_t)kt * 64, &Al[buf][(size_t)(l * 512 + w * 64) * 8]);
  };
  auto stB = [&](int kt, int buf, int l) {
    gload_lds16(bsrc[l] + (size_t)kt * 64, &Bl[buf][(size_t)(l * 512 + w * 64) * 8]);
  };

  stA(0, 0, 0); stA(0, 0, 1); stA(0, 0, 2); stA(0, 0, 3); stB(0, 0, 0); stB(0, 0, 1);
  stA(1, 1, 0); stA(1, 1, 1); stA(1, 1, 2); stA(1, 1, 3); stB(1, 1, 0); stB(1, 1, 1);
  WAITV6; BARX;

  f32x4 acc[4][4] = {};
  int cb = 0, nb = 2;
  for (int kt = 0; kt < NT; ++kt) {
    const unsigned short* Ac = &Al[cb][0];
    const unsigned short* Bc = &Bl[cb][0];
    const bool pf = (kt + 2 < NT);
    short8 a01[2][2], a23[2][2], bf[4][2];

#pragma unroll
    for (int i = 0; i < 2; ++i) {
      a01[i][0] = *(const short8*)&Ac[rA[i] + slA0];
      a01[i][1] = *(const short8*)&Ac[rA[i] + slA1];
    }
#pragma unroll
    for (int j = 0; j < 4; ++j) {
      bf[j][0] = *(const short8*)&Bc[rB[j] + slA0];
      bf[j][1] = *(const short8*)&Bc[rB[j] + slA1];
    }
    if (pf) { stA(kt + 2, nb, 0); stA(kt + 2, nb, 1); stA(kt + 2, nb, 2); }
    BARX;
    WAITL0; SCHED0;
    __builtin_amdgcn_s_setprio(1);
#pragma unroll
    for (int i = 0; i < 2; ++i)
#pragma unroll
      for (int j = 0; j < 4; ++j)
#pragma unroll
        for (int k = 0; k < 2; ++k)
          acc[i][j] = __builtin_amdgcn_mfma_f32_16x16x32_bf16(a01[i][k], bf[j][k], acc[i][j], 0, 0, 0);
    __builtin_amdgcn_s_setprio(0);
    BARX;

#pragma unroll
    for (int i = 0; i < 2; ++i) {
      a23[i][0] = *(const short8*)&Ac[rA[2 + i] + slA0];
      a23[i][1] = *(const short8*)&Ac[rA[2 + i] + slA1];
    }
    if (pf) { stA(kt + 2, nb, 3); stB(kt + 2, nb, 0); stB(kt + 2, nb, 1); }
    BARX;
    WAITL0; SCHED0;
    __builtin_amdgcn_s_setprio(1);
#pragma unroll
    for (int i = 0; i < 2; ++i)
#pragma unroll
      for (int j = 0; j < 4; ++j)
#pragma unroll
        for (int k = 0; k < 2; ++k)
          acc[2 + i][j] = __builtin_amdgcn_mfma_f32_16x16x32_bf16(a23[i][k], bf[j][k], acc[2 + i][j], 0, 0, 0);
    __builtin_amdgcn_s_setprio(0);
    if (kt < NT - 2) { WAITV6; }
    else if (kt == NT - 2) { WAITV0; }
    BARX;

    cb = (cb == 2) ? 0 : cb + 1;
    nb = (nb == 2) ? 0 : nb + 1;
  }

  if (EPI == 0) {
#pragma unroll
    for (int i = 0; i < 4; ++i)
#pragma unroll
      for (int j = 0; j < 4; ++j) {
        int colb = n0 + wn * 64 + j * 16;         // + ln15
        int z = colb >> 11;
        int c2 = (colb & 2047) + ln15;
        int h = c2 >> 7, d = c2 & 127;
        int m = m0 + wm * 64 + i * 16 + lq * 4;   // + rr
        int b = m >> 11, s = m & 2047;
        if (z == 2) {
          us4 pk;
#pragma unroll
          for (int r = 0; r < 4; ++r) pk[r] = f2bf(acc[i][j][r]);
          *(us4*)((unsigned short*)dv + (((size_t)b * NHc + h) * HDc + d) * SS + s) = pk;
        } else {
          // fused RoPE: partner dim d^1 lives in lane^1 (same i,j,r)
          unsigned short* D = (unsigned short*)(z ? dk : dq);
          const int fi = (d >> 1) & 31;
          const bool odd = (d & 1) != 0;
#pragma unroll
          for (int r = 0; r < 4; ++r) {
            float v = acc[i][j][r];
            float p = __shfl_xor(v, 1);
            float cs = cosT[(size_t)(s + r) * 32 + fi];
            float sn = sinT[(size_t)(s + r) * 32 + fi];
            float y = odd ? (p * sn + v * cs) : (v * cs - p * sn);
            D[(((size_t)b * NHc + h) * SS + s + r) * HDc + d] = f2bf(y);
          }
        }
      }
  } else {
    float* O = (float*)dq;
#pragma unroll
    for (int i = 0; i < 4; ++i)
#pragma unroll
      for (int j = 0; j < 4; ++j) {
        int col = n0 + wn * 64 + j * 16 + ln15;
        int m = m0 + wm * 64 + i * 16 + lq * 4;
#pragma unroll
        for (int r = 0; r < 4; ++r)
          O[(size_t)(m + r) * HIDc + col] = acc[i][j][r];
      }
  }
}

// ---------------------------------------------------------------------------
// 3) causal flash attention v9 — 8-wave SIMD-complementary blocks (R10) +
//    distance-2 counted-vmcnt staging: 3-deep K/V ring, stage kvt+2 at loop
//    top, vmcnt(4)+s_barrier per tile (never 0 until tail) — same
//    certification logic as gemm8's WAITV6 (proven race-free).
// ---------------------------------------------------------------------------
__global__ void __launch_bounds__(512, 2) attn_kernel(
    const unsigned short* __restrict__ Qg,
    const unsigned short* __restrict__ Kg,
    const unsigned short* __restrict__ Vg,   // [b][h][d][s]
    unsigned short* __restrict__ Og)
{
  __shared__ __align__(16) unsigned short Klds[3][64 * 128];   // [kv][d] swizzled
  __shared__ __align__(16) unsigned short Vlds[3][128 * 64];   // [d][kv] swizzled
  __shared__ __align__(16) unsigned short Plds[8][32 * 64];    // per-wave [q][kv] swizzled
  const int tid = threadIdx.x, lane = tid & 63, w = tid >> 6;
  const int l31 = lane & 31, hi = lane >> 5;

  const int wg = blockIdx.x;
  const int xcd = wg & 7, idx = wg >> 3;
  const int bh = xcd + 8 * (idx & 3);
  const int tt = idx >> 2;                   // 0..7

  const int qtile = (w < 2) ? tt : (w < 4) ? (tt + 8) : (w < 6) ? (31 - tt) : (23 - tt);
  const int sub1 = w & 1;
  const int q0w = qtile * 64 + sub1 * 32;
  const int ntiles = 32 - tt;                // >= 25

  const size_t hbase = (size_t)bh * SS * HDc;
  const float CE = 1.44269504089f * 0.08838834764831845f;  // log2(e)/sqrt(128)
  const int b = bh >> 4, h = bh & 15;

  short8 qf[8];
#pragma unroll
  for (int ks = 0; ks < 8; ++ks)
    qf[ks] = *(const short8*)(Qg + hbase + (size_t)(q0w + l31) * HDc + ks * 16 + hi * 8);

  f32x16 accO[4];
#pragma unroll
  for (int db = 0; db < 4; ++db)
#pragma unroll
    for (int r = 0; r < 16; ++r) accO[db][r] = 0.f;
  float mr = -1e30f, lr = 0.f;

  // 512 threads: 2 K-chunks + 2 V-chunks per thread per tile (4 loads)
  auto stage = [&](int kvt, int buf) {
    const int kv0 = kvt * 64;
#pragma unroll
    for (int p = 0; p < 2; ++p) {
      int c = p * 512 + tid;                 // 0..1023
      int krow = c >> 4, ksl = c & 15;
      gload_lds16(Kg + hbase + (size_t)(kv0 + krow) * HDc + ((ksl ^ (krow & 7)) << 3),
                  (unsigned short*)&Klds[buf][0] + (size_t)c * 8);
      int vd = c >> 3, vsl = c & 7;
      gload_lds16(Vg + hbase + (size_t)vd * SS + kv0 + ((vsl ^ (vd & 7)) << 3),
                  (unsigned short*)&Vlds[buf][0] + (size_t)c * 8);
    }
  };

  // prologue: stage tiles 0,1; certify tile 0 (vmcnt 4 + barrier)
  stage(0, 0); stage(1, 1);
  WAITV4; BARX;

  for (int kvt = 0; kvt < ntiles; ++kvt) {
    if (kvt + 2 < ntiles) stage(kvt + 2, (kvt + 2) % 3);
    const int cur = kvt % 3;

    if (kvt <= qtile) {
      const bool diag = (kvt == qtile);
      const bool haveT1 = (!diag) || sub1;

      f32x16 s0, s1;
#pragma unroll
      for (int r = 0; r < 16; ++r) s0[r] = 0.f;
      __builtin_amdgcn_s_setprio(1);
#pragma unroll
      for (int ks = 0; ks < 8; ++ks) {
        int row = l31;
        short8 kf = *(const short8*)&Klds[cur][row * 128 + (((2 * ks + hi) ^ (row & 7)) << 3)];
        s0 = __builtin_amdgcn_mfma_f32_32x32x16_bf16(kf, qf[ks], s0, 0, 0, 0);
      }
      if (haveT1) {
#pragma unroll
        for (int r = 0; r < 16; ++r) s1[r] = 0.f;
#pragma unroll
        for (int ks = 0; ks < 8; ++ks) {
          int row = 32 + l31;
          short8 kf = *(const short8*)&Klds[cur][row * 128 + (((2 * ks + hi) ^ (row & 7)) << 3)];
          s1 = __builtin_amdgcn_mfma_f32_32x32x16_bf16(kf, qf[ks], s1, 0, 0, 0);
        }
      }
      __builtin_amdgcn_s_setprio(0);

      if (diag) {
        if (sub1) {
#pragma unroll
          for (int r = 0; r < 16; ++r)
            if (((r & 3) + 8 * (r >> 2) + 4 * hi) > l31) s1[r] = -1e30f;
        } else {
#pragma unroll
          for (int r = 0; r < 16; ++r)
            if (((r & 3) + 8 * (r >> 2) + 4 * hi) > l31) s0[r] = -1e30f;
        }
      }

      float pmax = s0[0];
#pragma unroll
      for (int r = 1; r < 16; ++r) pmax = fmaxf(pmax, s0[r]);
      if (haveT1) {
#pragma unroll
        for (int r = 0; r < 16; ++r) pmax = fmaxf(pmax, s1[r]);
      }
      pmax = fmaxf(pmax, __shfl_xor(pmax, 32));

      int grow = (CE * (pmax - mr) > 8.0f) ? 1 : 0;
      if (__any(grow)) {
        float mn = fmaxf(mr, pmax);
        float al = exp2f(CE * (mr - mn));
        mr = mn; lr *= al;
        float alr[16];
#pragma unroll
        for (int r = 0; r < 16; ++r)
          alr[r] = __shfl(al, (r & 3) + 8 * (r >> 2) + 4 * hi);
#pragma unroll
        for (int db = 0; db < 4; ++db)
#pragma unroll
          for (int r = 0; r < 16; ++r) accO[db][r] *= alr[r];
      }

      float psum = 0.f;
#pragma unroll
      for (int r = 0; r < 16; ++r) {
        float p = exp2f(CE * (s0[r] - mr));
        s0[r] = p; psum += p;
      }
      if (haveT1) {
#pragma unroll
        for (int r = 0; r < 16; ++r) {
          float p = exp2f(CE * (s1[r] - mr));
          s1[r] = p; psum += p;
        }
      }
      psum += __shfl_xor(psum, 32);
      lr += psum;

#pragma unroll
      for (int i = 0; i < 4; ++i) {
        uint2v pk;
        pk[0] = cvtpk_bf16(s0[4 * i], s0[4 * i + 1]);
        pk[1] = cvtpk_bf16(s0[4 * i + 2], s0[4 * i + 3]);
        int chunk = i ^ (l31 & 7);
        *(uint2v*)&Plds[w][l31 * 64 + chunk * 8 + hi * 4] = pk;
      }
      if (haveT1) {
#pragma unroll
        for (int i = 0; i < 4; ++i) {
          uint2v pk;
          pk[0] = cvtpk_bf16(s1[4 * i], s1[4 * i + 1]);
          pk[1] = cvtpk_bf16(s1[4 * i + 2], s1[4 * i + 3]);
          int chunk = (4 + i) ^ (l31 & 7);
          *(uint2v*)&Plds[w][l31 * 64 + chunk * 8 + hi * 4] = pk;
        }
      }

      short8 ap[4];
#pragma unroll
      for (int ks = 0; ks < 2; ++ks)
        ap[ks] = *(const short8*)&Plds[w][l31 * 64 + (((2 * ks + hi) ^ (l31 & 7)) << 3)];
      if (haveT1) {
#pragma unroll
        for (int ks = 2; ks < 4; ++ks)
          ap[ks] = *(const short8*)&Plds[w][l31 * 64 + (((2 * ks + hi) ^ (l31 & 7)) << 3)];
      }

      __builtin_amdgcn_s_setprio(1);
#pragma unroll
      for (int db = 0; db < 4; ++db) {
        int row = db * 32 + l31;
#pragma unroll
        for (int ks = 0; ks < 2; ++ks) {
          short8 vf = *(const short8*)&Vlds[cur][row * 64 + (((2 * ks + hi) ^ (row & 7)) << 3)];
          accO[db] = __builtin_amdgcn_mfma_f32_32x32x16_bf16(ap[ks], vf, accO[db], 0, 0, 0);
        }
      }
      if (haveT1) {
#pragma unroll
        for (int db = 0; db < 4; ++db) {
          int row = db * 32 + l31;
#pragma unroll
          for (int ks = 2; ks < 4; ++ks) {
            short8 vf = *(const short8*)&Vlds[cur][row * 64 + (((2 * ks + hi) ^ (row & 7)) << 3)];
            accO[db] = __builtin_amdgcn_mfma_f32_32x32x16_bf16(ap[ks], vf, accO[db], 0, 0, 0);
          }
        }
      }
      __builtin_amdgcn_s_setprio(0);
    }

    // certify tile kvt+1 (all but newest stage) — never drain to 0 mid-loop
    if (kvt < ntiles - 2) { WAITV4; } else { WAITV0; }
    BARX;
  }

  float il = 1.0f / lr;
  float ilr[16];
#pragma unroll
  for (int r = 0; r < 16; ++r)
    ilr[r] = __shfl(il, (r & 3) + 8 * (r >> 2) + 4 * hi);
#pragma unroll
  for (int db = 0; db < 4; ++db)
#pragma unroll
    for (int r = 0; r < 16; ++r) {
      int q = q0w + (r & 3) + 8 * (r >> 2) + 4 * hi;
      int d = db * 32 + l31;
      Og[((size_t)b * SS + q) * HIDc + h * HDc + d] = f2bf(accO[db][r] * ilr[r]);
    }
}

// ---------------------------------------------------------------------------
extern "C" void kernel_launch(void* const* d_in, const int* in_sizes, int n_in,
                              void* d_out, int out_size, void* d_ws, size_t ws_size,
                              hipStream_t stream)
{
  if (ws_size < WS_NEED) return;

  const float* H  = (const float*)d_in[0];
  const float* Wq = (const float*)d_in[1];
  const float* Wk = (const float*)d_in[2];
  const float* Wv = (const float*)d_in[3];
  const float* Wo = (const float*)d_in[4];
  char* ws = (char*)d_ws;
  unsigned short* HB = (unsigned short*)(ws + OFF_HB);
  unsigned short* WB = (unsigned short*)(ws + OFF_WB);
  unsigned short* Qb = (unsigned short*)(ws + OFF_Q);
  unsigned short* Kb = (unsigned short*)(ws + OFF_K);
  unsigned short* Vb = (unsigned short*)(ws + OFF_V);
  unsigned short* AT = (unsigned short*)(ws + OFF_ATT);
  float* cosT = (float*)(ws + OFF_COS);
  float* sinT = (float*)(ws + OFF_SIN);

  cvt_kernel<<<12544, 256, 0, stream>>>(H, Wq, Wk, Wv, Wo, HB, cosT, sinT);
  // QKV: folded N = 6144, fused RoPE epilogue -> grid 8 XCD * 2 by * 48 bx = 768
  gemm8<0, 48><<<768, 512, 0, stream>>>(HB, WB, Qb, Kb, Vb, cosT, sinT);
  attn_kernel<<<256, 512, 0, stream>>>(Qb, Kb, Vb, AT);
  // proj: N = 2048 -> grid 8 * 2 * 16 = 256
  gemm8<1, 16><<<256, 512, 0, stream>>>(AT, WB + (size_t)3 * HIDc * KC,
                                        d_out, nullptr, nullptr, nullptr, nullptr);
}

// Round 14
// 258.029 us; speedup vs baseline: 1.1333x; 1.0139x over previous
//
#include <hip/hip_runtime.h>
#include <math.h>

typedef __attribute__((ext_vector_type(8))) short short8;
typedef __attribute__((ext_vector_type(4))) float f32x4;
typedef __attribute__((ext_vector_type(16))) float f32x16;
typedef __attribute__((ext_vector_type(4))) float fvec4;
typedef __attribute__((ext_vector_type(4))) unsigned short us4;
typedef __attribute__((ext_vector_type(2))) unsigned int uint2v;

#define DI __device__ __forceinline__
#define BARX asm volatile("s_barrier" ::: "memory")
#define WAITV6 asm volatile("s_waitcnt vmcnt(6)" ::: "memory")
#define WAITV4 asm volatile("s_waitcnt vmcnt(4)" ::: "memory")
#define WAITV0 asm volatile("s_waitcnt vmcnt(0)" ::: "memory")
#define WAITL0 asm volatile("s_waitcnt lgkmcnt(0)" ::: "memory")
#define SCHED0 __builtin_amdgcn_sched_barrier(0)

constexpr int BB = 2, SS = 2048, HIDc = 2048, NHc = 16, HDc = 128;
constexpr int MT = BB * SS;     // 4096 tokens
constexpr int KC = HIDc;        // 2048 inner dim

// ---- workspace layout (bytes) ----
constexpr size_t OFF_HB  = 0;                                      // H bf16   [4096][2048]
constexpr size_t OFF_WB  = OFF_HB + (size_t)MT * KC * 2;           // W bf16   4x[2048][2048]
constexpr size_t OFF_Q   = OFF_WB + (size_t)4 * HIDc * KC * 2;     // Q bf16   [b][h][s][d]
constexpr size_t OFF_K   = OFF_Q  + (size_t)BB * NHc * SS * HDc * 2;
constexpr size_t OFF_V   = OFF_K  + (size_t)BB * NHc * SS * HDc * 2; // V bf16 [b][h][d][s]
constexpr size_t OFF_ATT = OFF_V  + (size_t)BB * NHc * SS * HDc * 2; // attn bf16 [b*s][hid]
constexpr size_t OFF_COS = OFF_ATT + (size_t)MT * HIDc * 2;
constexpr size_t OFF_SIN = OFF_COS + (size_t)SS * 32 * 4;
constexpr size_t WS_NEED = OFF_SIN + (size_t)SS * 32 * 4;          // ~118 MB

DI float bf2f(unsigned short u) { union { unsigned u; float f; } v; v.u = (unsigned)u << 16; return v.f; }
DI unsigned short f2bf(float f) {
  union { float f; unsigned u; } v; v.f = f;
  unsigned r = v.u + 0x7fffu + ((v.u >> 16) & 1u);
  return (unsigned short)(r >> 16);
}

DI void gload_lds16(const void* g, void* l) {
  __builtin_amdgcn_global_load_lds((const __attribute__((address_space(1))) void*)g,
                                   (__attribute__((address_space(3))) void*)l, 16, 0, 0);
}

DI unsigned cvtpk_bf16(float lo, float hi_) {
  unsigned r;
  asm("v_cvt_pk_bf16_f32 %0, %1, %2" : "=v"(r) : "v"(lo), "v"(hi_));
  return r;
}

// ---------------------------------------------------------------------------
// 1) fp32 -> bf16 convert of H and the 4 weights + RoPE tables (fused tail)
// ---------------------------------------------------------------------------
__global__ void __launch_bounds__(256) cvt_kernel(
    const float* __restrict__ H,  const float* __restrict__ W0,
    const float* __restrict__ W1, const float* __restrict__ W2,
    const float* __restrict__ W3, unsigned short* __restrict__ dst,
    float* __restrict__ cosT, float* __restrict__ sinT)
{
  constexpr size_t HN = (size_t)MT * KC;      // 8388608
  constexpr size_t WN = (size_t)HIDc * KC;    // 4194304 = 2^22
  if (blockIdx.x >= 12288) {                  // RoPE-table tail blocks
    int idx = (blockIdx.x - 12288) * 256 + threadIdx.x;   // S*32 = 65536
    int t = idx >> 5, fi = idx & 31;
    float inv = powf(10000.0f, -(float)fi * (1.0f / 32.0f));
    float ang = (float)t * inv;
    cosT[idx] = cosf(ang);
    sinT[idx] = sinf(ang);
    return;
  }
  size_t e0 = ((size_t)blockIdx.x * 256 + threadIdx.x) * 8;
  const float* src; size_t off;
  if (e0 < HN) { src = H; off = e0; }
  else {
    size_t t = e0 - HN; int a = (int)(t >> 22);
    src = (a == 0) ? W0 : (a == 1) ? W1 : (a == 2) ? W2 : W3;
    off = t & (WN - 1);
  }
  fvec4 v0 = *(const fvec4*)(src + off);
  fvec4 v1 = *(const fvec4*)(src + off + 4);
  short8 o;
  o[0] = (short)f2bf(v0[0]); o[1] = (short)f2bf(v0[1]);
  o[2] = (short)f2bf(v0[2]); o[3] = (short)f2bf(v0[3]);
  o[4] = (short)f2bf(v1[0]); o[5] = (short)f2bf(v1[1]);
  o[6] = (short)f2bf(v1[2]); o[7] = (short)f2bf(v1[3]);
  *(short8*)(dst + e0) = o;
}

// ---------------------------------------------------------------------------
// 2a) QKV GEMM — 8-phase half-tile pipelined (m201-class port).
//     BM=BN=256, BK=64, 512 thr (8 waves 2m x 4n, per-wave 128x64 via
//     interleaved rowfrags: rows = 32f + 16wm). LDS = 8 slots x 16KB
//     (2 dbuf x 2 half x {A,B}) = 128 KiB. 1 half-tile (2 gloads) staged
//     per phase; vmcnt(6) at phases 4/8 (3 half-tiles in flight); barrier +
//     lgkmcnt(0) + 16-MFMA cluster per phase. Swizzle chunk^(row&7) both
//     sides. Slot-lifetime schedule verified: every stage >= 1 barrier after
//     its slot's last read; every K-tile certified before first consumption.
//     Folded N=6144 epilogue with fused RoPE (z<2) / V-transpose (z=2).
// ---------------------------------------------------------------------------
template<int NBX>
__global__ void __launch_bounds__(512, 2) gemm8p(
    const unsigned short* __restrict__ A,
    const unsigned short* __restrict__ Bw,
    void* __restrict__ dq, void* __restrict__ dk, void* __restrict__ dv,
    const float* __restrict__ cosT, const float* __restrict__ sinT)
{
  __shared__ __align__(16) unsigned short SL[8][128 * 64];  // 128 KiB
  const int tid = threadIdx.x, lane = tid & 63, w = tid >> 6;
  const int wm = w >> 2, wn = w & 3;        // 2m x 4n
  const int ln15 = lane & 15, lq = lane >> 4;

  const int xcd = blockIdx.x & 7, idx = blockIdx.x >> 3;
  const int by = xcd * 2 + idx / NBX, bx = idx % NBX;
  const int m0 = by * 256, n0 = bx * 256;

  // staging: thread covers rows (tid>>3) and 64+(tid>>3) within a 128-row half
  const int srow = tid >> 3;
  const int sc = (tid & 7) ^ (srow & 7);    // same for both rows (64 % 8 == 0)
  const unsigned short* Ab = A  + ((size_t)m0 + srow) * KC + sc * 8;
  const unsigned short* Bb = Bw + ((size_t)n0 + srow) * KC + sc * 8;

  constexpr int NT = KC / 64;               // 32 K-tiles
  auto stage = [&](int kt, bool isA, int half, int buf) {
    if (kt >= NT) return;
    const unsigned short* s = (isA ? Ab : Bb) + (size_t)(half * 128) * KC + kt * 64;
    int slot = (isA ? 0 : 4) + buf * 2 + half;
    unsigned short* d = &SL[slot][(size_t)(w * 64) * 8];
    gload_lds16(s, d);                         // rows 0..63 of half
    gload_lds16(s + (size_t)64 * KC, d + (size_t)512 * 8);  // rows 64..127
  };

  auto readA = [&](int buf, int q, int i, int ks) -> short8 {
    int rl = ((q & 1) << 6) + (i << 5) + (wm << 4) + ln15;   // row in half
    return *(const short8*)&SL[buf * 2 + (q >> 1)]
        [rl * 64 + ((((ks << 2) + lq) ^ (rl & 7)) << 3)];
  };
  auto readB = [&](int buf, int j, int ks) -> short8 {
    int rl = ((wn & 1) << 6) + (j << 4) + ln15;
    return *(const short8*)&SL[4 + buf * 2 + (wn >> 1)]
        [rl * 64 + ((((ks << 2) + lq) ^ (rl & 7)) << 3)];
  };

  // prologue: K0 full (4 halves) + K1 {B0,B1,A0}; certify K0
  stage(0, true, 0, 0); stage(0, true, 1, 0);
  stage(0, false, 0, 0); stage(0, false, 1, 0);
  stage(1, false, 0, 1); stage(1, false, 1, 1); stage(1, true, 0, 1);
  WAITV6; BARX;

  f32x4 acc[8][4] = {};
  short8 bfr[4][2];
  constexpr int NIT = NT / 2;               // 16 iterations x 2 K-tiles
  for (int t = 0; t < NIT; ++t) {
    const int k2 = 2 * t + 2, k3 = 2 * t + 3;
#pragma unroll
    for (int b = 0; b < 2; ++b) {
#pragma unroll
      for (int q = 0; q < 4; ++q) {
        short8 af[2][2];
#pragma unroll
        for (int i = 0; i < 2; ++i)
#pragma unroll
          for (int ks = 0; ks < 2; ++ks) af[i][ks] = readA(b, q, i, ks);
        if (q == 0) {
#pragma unroll
          for (int j = 0; j < 4; ++j)
#pragma unroll
            for (int ks = 0; ks < 2; ++ks) bfr[j][ks] = readB(b, j, ks);
        }
        // half-tile stage schedule (slot-lifetime verified)
        if (b == 0) {
          if (q == 0) stage(2 * t + 1, true, 1, 1);
          else if (q == 1) stage(k2, false, 0, 0);
          else if (q == 2) stage(k2, false, 1, 0);
          else stage(k2, true, 0, 0);
        } else {
          if (q == 0) stage(k2, true, 1, 0);
          else if (q == 1) stage(k3, false, 0, 1);
          else if (q == 2) stage(k3, false, 1, 1);
          else stage(k3, true, 0, 1);
        }
        BARX;
        WAITL0; SCHED0;
        __builtin_amdgcn_s_setprio(1);
#pragma unroll
        for (int i = 0; i < 2; ++i)
#pragma unroll
          for (int j = 0; j < 4; ++j)
#pragma unroll
            for (int ks = 0; ks < 2; ++ks)
              acc[2 * q + i][j] = __builtin_amdgcn_mfma_f32_16x16x32_bf16(
                  af[i][ks], bfr[j][ks], acc[2 * q + i][j], 0, 0, 0);
        __builtin_amdgcn_s_setprio(0);
        if (q == 3) { if (t == NIT - 1) { WAITV0; } else { WAITV6; } }
        BARX;
      }
    }
  }

  // ---- folded-N epilogue with fused RoPE ----
#pragma unroll
  for (int f = 0; f < 8; ++f)
#pragma unroll
    for (int j = 0; j < 4; ++j) {
      int col = n0 + wn * 64 + j * 16 + ln15;
      int z = col >> 11;
      int c2 = col & 2047;
      int h = c2 >> 7, d = c2 & 127;
      int m = m0 + 32 * f + 16 * wm + lq * 4;
      int b = m >> 11, s = m & 2047;
      if (z == 2) {
        us4 pk;
#pragma unroll
        for (int r = 0; r < 4; ++r) pk[r] = f2bf(acc[f][j][r]);
        *(us4*)((unsigned short*)dv + (((size_t)b * NHc + h) * HDc + d) * SS + s) = pk;
      } else {
        unsigned short* D = (unsigned short*)(z ? dk : dq);
        const int fi = (d >> 1) & 31;
        const bool odd = (d & 1) != 0;
#pragma unroll
        for (int r = 0; r < 4; ++r) {
          float v = acc[f][j][r];
          float p = __shfl_xor(v, 1);
          float cs = cosT[(size_t)(s + r) * 32 + fi];
          float sn = sinT[(size_t)(s + r) * 32 + fi];
          float y = odd ? (p * sn + v * cs) : (v * cs - p * sn);
          D[(((size_t)b * NHc + h) * SS + s + r) * HDc + d] = f2bf(y);
        }
      }
    }
}

// ---------------------------------------------------------------------------
// 2b) Pipelined bf16 GEMM (R8 structure — proj only): BM=256 BN=128 BK=64,
//     3-deep LDS ring, distance-2 prefetch, counted vmcnt(6).
// ---------------------------------------------------------------------------
template<int EPI, int NBX>
__global__ void __launch_bounds__(512, 2) gemm8(
    const unsigned short* __restrict__ A,
    const unsigned short* __restrict__ Bw,
    void* __restrict__ dq, void* __restrict__ dk, void* __restrict__ dv,
    const float* __restrict__ cosT, const float* __restrict__ sinT)
{
  __shared__ __align__(16) unsigned short Al[3][256 * 64];
  __shared__ __align__(16) unsigned short Bl[3][128 * 64];
  const int tid = threadIdx.x, lane = tid & 63, w = tid >> 6;
  const int wm = w >> 1, wn = w & 1;
  const int ln15 = lane & 15, lq = lane >> 4;

  const int xcd = blockIdx.x & 7, idx = blockIdx.x >> 3;
  const int by = xcd * 2 + idx / NBX, bx = idx % NBX;
  const int m0 = by * 256, n0 = bx * 128;

  const int srow = tid >> 3;                 // 0..63
  const int sc = (tid & 7) ^ (srow & 7);
  const unsigned short* asrc[4];
  const unsigned short* bsrc[2];
#pragma unroll
  for (int l = 0; l < 4; ++l) asrc[l] = A  + (size_t)(m0 + l * 64 + srow) * KC + sc * 8;
#pragma unroll
  for (int l = 0; l < 2; ++l) bsrc[l] = Bw + (size_t)(n0 + l * 64 + srow) * KC + sc * 8;

  const int x7 = ln15 & 7;
  const int slA0 = (lq ^ x7) * 8;
  const int slA1 = ((4 + lq) ^ x7) * 8;
  int rA[4], rB[4];
#pragma unroll
  for (int i = 0; i < 4; ++i) rA[i] = (wm * 64 + i * 16 + ln15) * 64;
#pragma unroll
  for (int j = 0; j < 4; ++j) rB[j] = (wn * 64 + j * 16 + ln15) * 64;

  constexpr int NT = KC / 64;   // 32
  auto stA = [&](int kt, int buf, int l) {
    gload_lds16(asrc[l] + (size_t)kt * 64, &Al[buf][(size_t)(l * 512 + w * 64) * 8]);
  };
  auto stB = [&](int kt, int buf, int l) {
    gload_lds16(bsrc[l] + (size_t)kt * 64, &Bl[buf][(size_t)(l * 512 + w * 64) * 8]);
  };

  stA(0, 0, 0); stA(0, 0, 1); stA(0, 0, 2); stA(0, 0, 3); stB(0, 0, 0); stB(0, 0, 1);
  stA(1, 1, 0); stA(1, 1, 1); stA(1, 1, 2); stA(1, 1, 3); stB(1, 1, 0); stB(1, 1, 1);
  WAITV6; BARX;

  f32x4 acc[4][4] = {};
  int cb = 0, nb = 2;
  for (int kt = 0; kt < NT; ++kt) {
    const unsigned short* Ac = &Al[cb][0];
    const unsigned short* Bc = &Bl[cb][0];
    const bool pf = (kt + 2 < NT);
    short8 a01[2][2], a23[2][2], bf[4][2];

#pragma unroll
    for (int i = 0; i < 2; ++i) {
      a01[i][0] = *(const short8*)&Ac[rA[i] + slA0];
      a01[i][1] = *(const short8*)&Ac[rA[i] + slA1];
    }
#pragma unroll
    for (int j = 0; j < 4; ++j) {
      bf[j][0] = *(const short8*)&Bc[rB[j] + slA0];
      bf[j][1] = *(const short8*)&Bc[rB[j] + slA1];
    }
    if (pf) { stA(kt + 2, nb, 0); stA(kt + 2, nb, 1); stA(kt + 2, nb, 2); }
    BARX;
    WAITL0; SCHED0;
    __builtin_amdgcn_s_setprio(1);
#pragma unroll
    for (int i = 0; i < 2; ++i)
#pragma unroll
      for (int j = 0; j < 4; ++j)
#pragma unroll
        for (int k = 0; k < 2; ++k)
          acc[i][j] = __builtin_amdgcn_mfma_f32_16x16x32_bf16(a01[i][k], bf[j][k], acc[i][j], 0, 0, 0);
    __builtin_amdgcn_s_setprio(0);
    BARX;

#pragma unroll
    for (int i = 0; i < 2; ++i) {
      a23[i][0] = *(const short8*)&Ac[rA[2 + i] + slA0];
      a23[i][1] = *(const short8*)&Ac[rA[2 + i] + slA1];
    }
    if (pf) { stA(kt + 2, nb, 3); stB(kt + 2, nb, 0); stB(kt + 2, nb, 1); }
    BARX;
    WAITL0; SCHED0;
    __builtin_amdgcn_s_setprio(1);
#pragma unroll
    for (int i = 0; i < 2; ++i)
#pragma unroll
      for (int j = 0; j < 4; ++j)
#pragma unroll
        for (int k = 0; k < 2; ++k)
          acc[2 + i][j] = __builtin_amdgcn_mfma_f32_16x16x32_bf16(a23[i][k], bf[j][k], acc[2 + i][j], 0, 0, 0);
    __builtin_amdgcn_s_setprio(0);
    if (kt < NT - 2) { WAITV6; }
    else if (kt == NT - 2) { WAITV0; }
    BARX;

    cb = (cb == 2) ? 0 : cb + 1;
    nb = (nb == 2) ? 0 : nb + 1;
  }

  if (EPI == 0) {
#pragma unroll
    for (int i = 0; i < 4; ++i)
#pragma unroll
      for (int j = 0; j < 4; ++j) {
        int colb = n0 + wn * 64 + j * 16;
        int z = colb >> 11;
        int c2 = (colb & 2047) + ln15;
        int h = c2 >> 7, d = c2 & 127;
        int m = m0 + wm * 64 + i * 16 + lq * 4;
        int b = m >> 11, s = m & 2047;
        if (z == 2) {
          us4 pk;
#pragma unroll
          for (int r = 0; r < 4; ++r) pk[r] = f2bf(acc[i][j][r]);
          *(us4*)((unsigned short*)dv + (((size_t)b * NHc + h) * HDc + d) * SS + s) = pk;
        } else {
          unsigned short* D = (unsigned short*)(z ? dk : dq);
          const int fi = (c2 >> 1) & 31;
          const bool odd = (c2 & 1) != 0;
#pragma unroll
          for (int r = 0; r < 4; ++r) {
            float v = acc[i][j][r];
            float p = __shfl_xor(v, 1);
            float cs = cosT[(size_t)(s + r) * 32 + fi];
            float sn = sinT[(size_t)(s + r) * 32 + fi];
            float y = odd ? (p * sn + v * cs) : (v * cs - p * sn);
            D[(((size_t)b * NHc + h) * SS + s + r) * HDc + d] = f2bf(y);
          }
        }
      }
  } else {
    float* O = (float*)dq;
#pragma unroll
    for (int i = 0; i < 4; ++i)
#pragma unroll
      for (int j = 0; j < 4; ++j) {
        int col = n0 + wn * 64 + j * 16 + ln15;
        int m = m0 + wm * 64 + i * 16 + lq * 4;
#pragma unroll
        for (int r = 0; r < 4; ++r)
          O[(size_t)(m + r) * HIDc + col] = acc[i][j][r];
      }
  }
}

// ---------------------------------------------------------------------------
// 3) causal flash attention v9 (R13 structure, unchanged)
// ---------------------------------------------------------------------------
__global__ void __launch_bounds__(512, 2) attn_kernel(
    const unsigned short* __restrict__ Qg,
    const unsigned short* __restrict__ Kg,
    const unsigned short* __restrict__ Vg,   // [b][h][d][s]
    unsigned short* __restrict__ Og)
{
  __shared__ __align__(16) unsigned short Klds[3][64 * 128];   // [kv][d] swizzled
  __shared__ __align__(16) unsigned short Vlds[3][128 * 64];   // [d][kv] swizzled
  __shared__ __align__(16) unsigned short Plds[8][32 * 64];    // per-wave [q][kv] swizzled
  const int tid = threadIdx.x, lane = tid & 63, w = tid >> 6;
  const int l31 = lane & 31, hi = lane >> 5;

  const int wg = blockIdx.x;
  const int xcd = wg & 7, idx = wg >> 3;
  const int bh = xcd + 8 * (idx & 3);
  const int tt = idx >> 2;                   // 0..7

  const int qtile = (w < 2) ? tt : (w < 4) ? (tt + 8) : (w < 6) ? (31 - tt) : (23 - tt);
  const int sub1 = w & 1;
  const int q0w = qtile * 64 + sub1 * 32;
  const int ntiles = 32 - tt;                // >= 25

  const size_t hbase = (size_t)bh * SS * HDc;
  const float CE = 1.44269504089f * 0.08838834764831845f;  // log2(e)/sqrt(128)
  const int b = bh >> 4, h = bh & 15;

  short8 qf[8];
#pragma unroll
  for (int ks = 0; ks < 8; ++ks)
    qf[ks] = *(const short8*)(Qg + hbase + (size_t)(q0w + l31) * HDc + ks * 16 + hi * 8);

  f32x16 accO[4];
#pragma unroll
  for (int db = 0; db < 4; ++db)
#pragma unroll
    for (int r = 0; r < 16; ++r) accO[db][r] = 0.f;
  float mr = -1e30f, lr = 0.f;

  auto stage = [&](int kvt, int buf) {
    const int kv0 = kvt * 64;
#pragma unroll
    for (int p = 0; p < 2; ++p) {
      int c = p * 512 + tid;                 // 0..1023
      int krow = c >> 4, ksl = c & 15;
      gload_lds16(Kg + hbase + (size_t)(kv0 + krow) * HDc + ((ksl ^ (krow & 7)) << 3),
                  (unsigned short*)&Klds[buf][0] + (size_t)c * 8);
      int vd = c >> 3, vsl = c & 7;
      gload_lds16(Vg + hbase + (size_t)vd * SS + kv0 + ((vsl ^ (vd & 7)) << 3),
                  (unsigned short*)&Vlds[buf][0] + (size_t)c * 8);
    }
  };

  stage(0, 0); stage(1, 1);
  WAITV4; BARX;

  for (int kvt = 0; kvt < ntiles; ++kvt) {
    if (kvt + 2 < ntiles) stage(kvt + 2, (kvt + 2) % 3);
    const int cur = kvt % 3;

    if (kvt <= qtile) {
      const bool diag = (kvt == qtile);
      const bool haveT1 = (!diag) || sub1;

      f32x16 s0, s1;
#pragma unroll
      for (int r = 0; r < 16; ++r) s0[r] = 0.f;
      __builtin_amdgcn_s_setprio(1);
#pragma unroll
      for (int ks = 0; ks < 8; ++ks) {
        int row = l31;
        short8 kf = *(const short8*)&Klds[cur][row * 128 + (((2 * ks + hi) ^ (row & 7)) << 3)];
        s0 = __builtin_amdgcn_mfma_f32_32x32x16_bf16(kf, qf[ks], s0, 0, 0, 0);
      }
      if (haveT1) {
#pragma unroll
        for (int r = 0; r < 16; ++r) s1[r] = 0.f;
#pragma unroll
        for (int ks = 0; ks < 8; ++ks) {
          int row = 32 + l31;
          short8 kf = *(const short8*)&Klds[cur][row * 128 + (((2 * ks + hi) ^ (row & 7)) << 3)];
          s1 = __builtin_amdgcn_mfma_f32_32x32x16_bf16(kf, qf[ks], s1, 0, 0, 0);
        }
      }
      __builtin_amdgcn_s_setprio(0);

      if (diag) {
        if (sub1) {
#pragma unroll
          for (int r = 0; r < 16; ++r)
            if (((r & 3) + 8 * (r >> 2) + 4 * hi) > l31) s1[r] = -1e30f;
        } else {
#pragma unroll
          for (int r = 0; r < 16; ++r)
            if (((r & 3) + 8 * (r >> 2) + 4 * hi) > l31) s0[r] = -1e30f;
        }
      }

      float pmax = s0[0];
#pragma unroll
      for (int r = 1; r < 16; ++r) pmax = fmaxf(pmax, s0[r]);
      if (haveT1) {
#pragma unroll
        for (int r = 0; r < 16; ++r) pmax = fmaxf(pmax, s1[r]);
      }
      pmax = fmaxf(pmax, __shfl_xor(pmax, 32));

      int grow = (CE * (pmax - mr) > 8.0f) ? 1 : 0;
      if (__any(grow)) {
        float mn = fmaxf(mr, pmax);
        float al = exp2f(CE * (mr - mn));
        mr = mn; lr *= al;
        float alr[16];
#pragma unroll
        for (int r = 0; r < 16; ++r)
          alr[r] = __shfl(al, (r & 3) + 8 * (r >> 2) + 4 * hi);
#pragma unroll
        for (int db = 0; db < 4; ++db)
#pragma unroll
          for (int r = 0; r < 16; ++r) accO[db][r] *= alr[r];
      }

      float psum = 0.f;
#pragma unroll
      for (int r = 0; r < 16; ++r) {
        float p = exp2f(CE * (s0[r] - mr));
        s0[r] = p; psum += p;
      }
      if (haveT1) {
#pragma unroll
        for (int r = 0; r < 16; ++r) {
          float p = exp2f(CE * (s1[r] - mr));
          s1[r] = p; psum += p;
        }
      }
      psum += __shfl_xor(psum, 32);
      lr += psum;

#pragma unroll
      for (int i = 0; i < 4; ++i) {
        uint2v pk;
        pk[0] = cvtpk_bf16(s0[4 * i], s0[4 * i + 1]);
        pk[1] = cvtpk_bf16(s0[4 * i + 2], s0[4 * i + 3]);
        int chunk = i ^ (l31 & 7);
        *(uint2v*)&Plds[w][l31 * 64 + chunk * 8 + hi * 4] = pk;
      }
      if (haveT1) {
#pragma unroll
        for (int i = 0; i < 4; ++i) {
          uint2v pk;
          pk[0] = cvtpk_bf16(s1[4 * i], s1[4 * i + 1]);
          pk[1] = cvtpk_bf16(s1[4 * i + 2], s1[4 * i + 3]);
          int chunk = (4 + i) ^ (l31 & 7);
          *(uint2v*)&Plds[w][l31 * 64 + chunk * 8 + hi * 4] = pk;
        }
      }

      short8 ap[4];
#pragma unroll
      for (int ks = 0; ks < 2; ++ks)
        ap[ks] = *(const short8*)&Plds[w][l31 * 64 + (((2 * ks + hi) ^ (l31 & 7)) << 3)];
      if (haveT1) {
#pragma unroll
        for (int ks = 2; ks < 4; ++ks)
          ap[ks] = *(const short8*)&Plds[w][l31 * 64 + (((2 * ks + hi) ^ (l31 & 7)) << 3)];
      }

      __builtin_amdgcn_s_setprio(1);
#pragma unroll
      for (int db = 0; db < 4; ++db) {
        int row = db * 32 + l31;
#pragma unroll
        for (int ks = 0; ks < 2; ++ks) {
          short8 vf = *(const short8*)&Vlds[cur][row * 64 + (((2 * ks + hi) ^ (row & 7)) << 3)];
          accO[db] = __builtin_amdgcn_mfma_f32_32x32x16_bf16(ap[ks], vf, accO[db], 0, 0, 0);
        }
      }
      if (haveT1) {
#pragma unroll
        for (int db = 0; db < 4; ++db) {
          int row = db * 32 + l31;
#pragma unroll
          for (int ks = 2; ks < 4; ++ks) {
            short8 vf = *(const short8*)&Vlds[cur][row * 64 + (((2 * ks + hi) ^ (row & 7)) << 3)];
            accO[db] = __builtin_amdgcn_mfma_f32_32x32x16_bf16(ap[ks], vf, accO[db], 0, 0, 0);
          }
        }
      }
      __builtin_amdgcn_s_setprio(0);
    }

    if (kvt < ntiles - 2) { WAITV4; } else { WAITV0; }
    BARX;
  }

  float il = 1.0f / lr;
  float ilr[16];
#pragma unroll
  for (int r = 0; r < 16; ++r)
    ilr[r] = __shfl(il, (r & 3) + 8 * (r >> 2) + 4 * hi);
#pragma unroll
  for (int db = 0; db < 4; ++db)
#pragma unroll
    for (int r = 0; r < 16; ++r) {
      int q = q0w + (r & 3) + 8 * (r >> 2) + 4 * hi;
      int d = db * 32 + l31;
      Og[((size_t)b * SS + q) * HIDc + h * HDc + d] = f2bf(accO[db][r] * ilr[r]);
    }
}

// ---------------------------------------------------------------------------
extern "C" void kernel_launch(void* const* d_in, const int* in_sizes, int n_in,
                              void* d_out, int out_size, void* d_ws, size_t ws_size,
                              hipStream_t stream)
{
  if (ws_size < WS_NEED) return;

  const float* H  = (const float*)d_in[0];
  const float* Wq = (const float*)d_in[1];
  const float* Wk = (const float*)d_in[2];
  const float* Wv = (const float*)d_in[3];
  const float* Wo = (const float*)d_in[4];
  char* ws = (char*)d_ws;
  unsigned short* HB = (unsigned short*)(ws + OFF_HB);
  unsigned short* WB = (unsigned short*)(ws + OFF_WB);
  unsigned short* Qb = (unsigned short*)(ws + OFF_Q);
  unsigned short* Kb = (unsigned short*)(ws + OFF_K);
  unsigned short* Vb = (unsigned short*)(ws + OFF_V);
  unsigned short* AT = (unsigned short*)(ws + OFF_ATT);
  float* cosT = (float*)(ws + OFF_COS);
  float* sinT = (float*)(ws + OFF_SIN);

  cvt_kernel<<<12544, 256, 0, stream>>>(H, Wq, Wk, Wv, Wo, HB, cosT, sinT);
  // QKV: 8-phase 256x256, folded N = 6144 -> grid 8 XCD * 2 by * 24 bx = 384
  gemm8p<24><<<384, 512, 0, stream>>>(HB, WB, Qb, Kb, Vb, cosT, sinT);
  attn_kernel<<<256, 512, 0, stream>>>(Qb, Kb, Vb, AT);
  // proj: N = 2048 -> grid 8 * 2 * 16 = 256
  gemm8<1, 16><<<256, 512, 0, stream>>>(AT, WB + (size_t)3 * HIDc * KC,
                                        d_out, nullptr, nullptr, nullptr, nullptr);
}

// Round 15
// 243.642 us; speedup vs baseline: 1.2002x; 1.0590x over previous
//
#include <hip/hip_runtime.h>
#include <math.h>

typedef __attribute__((ext_vector_type(8))) short short8;
typedef __attribute__((ext_vector_type(4))) float f32x4;
typedef __attribute__((ext_vector_type(16))) float f32x16;
typedef __attribute__((ext_vector_type(4))) float fvec4;
typedef __attribute__((ext_vector_type(4))) unsigned short us4;
typedef __attribute__((ext_vector_type(2))) unsigned int uint2v;

#define DI __device__ __forceinline__
#define BARX asm volatile("s_barrier" ::: "memory")
#define WAITV6 asm volatile("s_waitcnt vmcnt(6)" ::: "memory")
#define WAITV4 asm volatile("s_waitcnt vmcnt(4)" ::: "memory")
#define WAITV0 asm volatile("s_waitcnt vmcnt(0)" ::: "memory")
#define WAITL0 asm volatile("s_waitcnt lgkmcnt(0)" ::: "memory")
#define SCHED0 __builtin_amdgcn_sched_barrier(0)

constexpr int BB = 2, SS = 2048, HIDc = 2048, NHc = 16, HDc = 128;
constexpr int MT = BB * SS;     // 4096 tokens
constexpr int KC = HIDc;        // 2048 inner dim

// ---- workspace layout (bytes) ----
constexpr size_t OFF_HB  = 0;                                      // H bf16   [4096][2048]
constexpr size_t OFF_WB  = OFF_HB + (size_t)MT * KC * 2;           // W bf16   4x[2048][2048]
constexpr size_t OFF_Q   = OFF_WB + (size_t)4 * HIDc * KC * 2;     // Q bf16   [b][h][s][d]
constexpr size_t OFF_K   = OFF_Q  + (size_t)BB * NHc * SS * HDc * 2;
constexpr size_t OFF_V   = OFF_K  + (size_t)BB * NHc * SS * HDc * 2; // V bf16 [b][h][d][s]
constexpr size_t OFF_ATT = OFF_V  + (size_t)BB * NHc * SS * HDc * 2; // attn bf16 [b*s][hid]
constexpr size_t OFF_COS = OFF_ATT + (size_t)MT * HIDc * 2;
constexpr size_t OFF_SIN = OFF_COS + (size_t)SS * 32 * 4;
constexpr size_t WS_NEED = OFF_SIN + (size_t)SS * 32 * 4;          // ~118 MB

DI float bf2f(unsigned short u) { union { unsigned u; float f; } v; v.u = (unsigned)u << 16; return v.f; }
DI unsigned short f2bf(float f) {
  union { float f; unsigned u; } v; v.f = f;
  unsigned r = v.u + 0x7fffu + ((v.u >> 16) & 1u);
  return (unsigned short)(r >> 16);
}

DI void gload_lds16(const void* g, void* l) {
  __builtin_amdgcn_global_load_lds((const __attribute__((address_space(1))) void*)g,
                                   (__attribute__((address_space(3))) void*)l, 16, 0, 0);
}

DI unsigned cvtpk_bf16(float lo, float hi_) {
  unsigned r;
  asm("v_cvt_pk_bf16_f32 %0, %1, %2" : "=v"(r) : "v"(lo), "v"(hi_));
  return r;
}

// ---------------------------------------------------------------------------
// 1) fp32 -> bf16 convert of H and the 4 weights + RoPE tables (fused tail)
// ---------------------------------------------------------------------------
__global__ void __launch_bounds__(256) cvt_kernel(
    const float* __restrict__ H,  const float* __restrict__ W0,
    const float* __restrict__ W1, const float* __restrict__ W2,
    const float* __restrict__ W3, unsigned short* __restrict__ dst,
    float* __restrict__ cosT, float* __restrict__ sinT)
{
  constexpr size_t HN = (size_t)MT * KC;      // 8388608
  constexpr size_t WN = (size_t)HIDc * KC;    // 4194304 = 2^22
  if (blockIdx.x >= 12288) {                  // RoPE-table tail blocks
    int idx = (blockIdx.x - 12288) * 256 + threadIdx.x;   // S*32 = 65536
    int t = idx >> 5, fi = idx & 31;
    float inv = powf(10000.0f, -(float)fi * (1.0f / 32.0f));
    float ang = (float)t * inv;
    cosT[idx] = cosf(ang);
    sinT[idx] = sinf(ang);
    return;
  }
  size_t e0 = ((size_t)blockIdx.x * 256 + threadIdx.x) * 8;
  const float* src; size_t off;
  if (e0 < HN) { src = H; off = e0; }
  else {
    size_t t = e0 - HN; int a = (int)(t >> 22);
    src = (a == 0) ? W0 : (a == 1) ? W1 : (a == 2) ? W2 : W3;
    off = t & (WN - 1);
  }
  fvec4 v0 = *(const fvec4*)(src + off);
  fvec4 v1 = *(const fvec4*)(src + off + 4);
  short8 o;
  o[0] = (short)f2bf(v0[0]); o[1] = (short)f2bf(v0[1]);
  o[2] = (short)f2bf(v0[2]); o[3] = (short)f2bf(v0[3]);
  o[4] = (short)f2bf(v1[0]); o[5] = (short)f2bf(v1[1]);
  o[6] = (short)f2bf(v1[2]); o[7] = (short)f2bf(v1[3]);
  *(short8*)(dst + e0) = o;
}

// ---------------------------------------------------------------------------
// 2a) QK GEMM — 8-phase half-tile pipelined (R14 structure, unchanged).
//     Launched on folded N=4096 (Q,K) -> 256 blocks = exactly 1 residency
//     round at 1 block/CU (no grid tail).
// ---------------------------------------------------------------------------
template<int NBX>
__global__ void __launch_bounds__(512, 2) gemm8p(
    const unsigned short* __restrict__ A,
    const unsigned short* __restrict__ Bw,
    void* __restrict__ dq, void* __restrict__ dk, void* __restrict__ dv,
    const float* __restrict__ cosT, const float* __restrict__ sinT)
{
  __shared__ __align__(16) unsigned short SL[8][128 * 64];  // 128 KiB
  const int tid = threadIdx.x, lane = tid & 63, w = tid >> 6;
  const int wm = w >> 2, wn = w & 3;        // 2m x 4n
  const int ln15 = lane & 15, lq = lane >> 4;

  const int xcd = blockIdx.x & 7, idx = blockIdx.x >> 3;
  const int by = xcd * 2 + idx / NBX, bx = idx % NBX;
  const int m0 = by * 256, n0 = bx * 256;

  const int srow = tid >> 3;
  const int sc = (tid & 7) ^ (srow & 7);
  const unsigned short* Ab = A  + ((size_t)m0 + srow) * KC + sc * 8;
  const unsigned short* Bb = Bw + ((size_t)n0 + srow) * KC + sc * 8;

  constexpr int NT = KC / 64;               // 32 K-tiles
  auto stage = [&](int kt, bool isA, int half, int buf) {
    if (kt >= NT) return;
    const unsigned short* s = (isA ? Ab : Bb) + (size_t)(half * 128) * KC + kt * 64;
    int slot = (isA ? 0 : 4) + buf * 2 + half;
    unsigned short* d = &SL[slot][(size_t)(w * 64) * 8];
    gload_lds16(s, d);
    gload_lds16(s + (size_t)64 * KC, d + (size_t)512 * 8);
  };

  auto readA = [&](int buf, int q, int i, int ks) -> short8 {
    int rl = ((q & 1) << 6) + (i << 5) + (wm << 4) + ln15;
    return *(const short8*)&SL[buf * 2 + (q >> 1)]
        [rl * 64 + ((((ks << 2) + lq) ^ (rl & 7)) << 3)];
  };
  auto readB = [&](int buf, int j, int ks) -> short8 {
    int rl = ((wn & 1) << 6) + (j << 4) + ln15;
    return *(const short8*)&SL[4 + buf * 2 + (wn >> 1)]
        [rl * 64 + ((((ks << 2) + lq) ^ (rl & 7)) << 3)];
  };

  stage(0, true, 0, 0); stage(0, true, 1, 0);
  stage(0, false, 0, 0); stage(0, false, 1, 0);
  stage(1, false, 0, 1); stage(1, false, 1, 1); stage(1, true, 0, 1);
  WAITV6; BARX;

  f32x4 acc[8][4] = {};
  short8 bfr[4][2];
  constexpr int NIT = NT / 2;               // 16 iterations x 2 K-tiles
  for (int t = 0; t < NIT; ++t) {
    const int k2 = 2 * t + 2, k3 = 2 * t + 3;
#pragma unroll
    for (int b = 0; b < 2; ++b) {
#pragma unroll
      for (int q = 0; q < 4; ++q) {
        short8 af[2][2];
#pragma unroll
        for (int i = 0; i < 2; ++i)
#pragma unroll
          for (int ks = 0; ks < 2; ++ks) af[i][ks] = readA(b, q, i, ks);
        if (q == 0) {
#pragma unroll
          for (int j = 0; j < 4; ++j)
#pragma unroll
            for (int ks = 0; ks < 2; ++ks) bfr[j][ks] = readB(b, j, ks);
        }
        if (b == 0) {
          if (q == 0) stage(2 * t + 1, true, 1, 1);
          else if (q == 1) stage(k2, false, 0, 0);
          else if (q == 2) stage(k2, false, 1, 0);
          else stage(k2, true, 0, 0);
        } else {
          if (q == 0) stage(k2, true, 1, 0);
          else if (q == 1) stage(k3, false, 0, 1);
          else if (q == 2) stage(k3, false, 1, 1);
          else stage(k3, true, 0, 1);
        }
        BARX;
        WAITL0; SCHED0;
        __builtin_amdgcn_s_setprio(1);
#pragma unroll
        for (int i = 0; i < 2; ++i)
#pragma unroll
          for (int j = 0; j < 4; ++j)
#pragma unroll
            for (int ks = 0; ks < 2; ++ks)
              acc[2 * q + i][j] = __builtin_amdgcn_mfma_f32_16x16x32_bf16(
                  af[i][ks], bfr[j][ks], acc[2 * q + i][j], 0, 0, 0);
        __builtin_amdgcn_s_setprio(0);
        if (q == 3) { if (t == NIT - 1) { WAITV0; } else { WAITV6; } }
        BARX;
      }
    }
  }

  // ---- folded-N epilogue with fused RoPE (z in {0,1} for N=4096) ----
#pragma unroll
  for (int f = 0; f < 8; ++f)
#pragma unroll
    for (int j = 0; j < 4; ++j) {
      int col = n0 + wn * 64 + j * 16 + ln15;
      int z = col >> 11;
      int c2 = col & 2047;
      int h = c2 >> 7, d = c2 & 127;
      int m = m0 + 32 * f + 16 * wm + lq * 4;
      int b = m >> 11, s = m & 2047;
      if (z == 2) {
        us4 pk;
#pragma unroll
        for (int r = 0; r < 4; ++r) pk[r] = f2bf(acc[f][j][r]);
        *(us4*)((unsigned short*)dv + (((size_t)b * NHc + h) * HDc + d) * SS + s) = pk;
      } else {
        unsigned short* D = (unsigned short*)(z ? dk : dq);
        const int fi = (d >> 1) & 31;
        const bool odd = (d & 1) != 0;
#pragma unroll
        for (int r = 0; r < 4; ++r) {
          float v = acc[f][j][r];
          float p = __shfl_xor(v, 1);
          float cs = cosT[(size_t)(s + r) * 32 + fi];
          float sn = sinT[(size_t)(s + r) * 32 + fi];
          float y = odd ? (p * sn + v * cs) : (v * cs - p * sn);
          D[(((size_t)b * NHc + h) * SS + s + r) * HDc + d] = f2bf(y);
        }
      }
    }
}

// ---------------------------------------------------------------------------
// 2b) Pipelined bf16 GEMM (R8 structure): BM=256 BN=128 BK=64, 3-deep ring,
//     distance-2 prefetch, counted vmcnt(6), 2 phases x 16-MFMA clusters.
//     EPI 1: fp32 row-major (proj).  EPI 2: V-transpose [b][h][d][s] (N=2048).
// ---------------------------------------------------------------------------
template<int EPI, int NBX>
__global__ void __launch_bounds__(512, 2) gemm8(
    const unsigned short* __restrict__ A,
    const unsigned short* __restrict__ Bw,
    void* __restrict__ dq, void* __restrict__ dk, void* __restrict__ dv,
    const float* __restrict__ cosT, const float* __restrict__ sinT)
{
  __shared__ __align__(16) unsigned short Al[3][256 * 64];
  __shared__ __align__(16) unsigned short Bl[3][128 * 64];
  const int tid = threadIdx.x, lane = tid & 63, w = tid >> 6;
  const int wm = w >> 1, wn = w & 1;
  const int ln15 = lane & 15, lq = lane >> 4;

  const int xcd = blockIdx.x & 7, idx = blockIdx.x >> 3;
  const int by = xcd * 2 + idx / NBX, bx = idx % NBX;
  const int m0 = by * 256, n0 = bx * 128;

  const int srow = tid >> 3;                 // 0..63
  const int sc = (tid & 7) ^ (srow & 7);
  const unsigned short* asrc[4];
  const unsigned short* bsrc[2];
#pragma unroll
  for (int l = 0; l < 4; ++l) asrc[l] = A  + (size_t)(m0 + l * 64 + srow) * KC + sc * 8;
#pragma unroll
  for (int l = 0; l < 2; ++l) bsrc[l] = Bw + (size_t)(n0 + l * 64 + srow) * KC + sc * 8;

  const int x7 = ln15 & 7;
  const int slA0 = (lq ^ x7) * 8;
  const int slA1 = ((4 + lq) ^ x7) * 8;
  int rA[4], rB[4];
#pragma unroll
  for (int i = 0; i < 4; ++i) rA[i] = (wm * 64 + i * 16 + ln15) * 64;
#pragma unroll
  for (int j = 0; j < 4; ++j) rB[j] = (wn * 64 + j * 16 + ln15) * 64;

  constexpr int NT = KC / 64;   // 32
  auto stA = [&](int kt, int buf, int l) {
    gload_lds16(asrc[l] + (size_t)kt * 64, &Al[buf][(size_t)(l * 512 + w * 64) * 8]);
  };
  auto stB = [&](int kt, int buf, int l) {
    gload_lds16(bsrc[l] + (size_t)kt * 64, &Bl[buf][(size_t)(l * 512 + w * 64) * 8]);
  };

  stA(0, 0, 0); stA(0, 0, 1); stA(0, 0, 2); stA(0, 0, 3); stB(0, 0, 0); stB(0, 0, 1);
  stA(1, 1, 0); stA(1, 1, 1); stA(1, 1, 2); stA(1, 1, 3); stB(1, 1, 0); stB(1, 1, 1);
  WAITV6; BARX;

  f32x4 acc[4][4] = {};
  int cb = 0, nb = 2;
  for (int kt = 0; kt < NT; ++kt) {
    const unsigned short* Ac = &Al[cb][0];
    const unsigned short* Bc = &Bl[cb][0];
    const bool pf = (kt + 2 < NT);
    short8 a01[2][2], a23[2][2], bf[4][2];

#pragma unroll
    for (int i = 0; i < 2; ++i) {
      a01[i][0] = *(const short8*)&Ac[rA[i] + slA0];
      a01[i][1] = *(const short8*)&Ac[rA[i] + slA1];
    }
#pragma unroll
    for (int j = 0; j < 4; ++j) {
      bf[j][0] = *(const short8*)&Bc[rB[j] + slA0];
      bf[j][1] = *(const short8*)&Bc[rB[j] + slA1];
    }
    if (pf) { stA(kt + 2, nb, 0); stA(kt + 2, nb, 1); stA(kt + 2, nb, 2); }
    BARX;
    WAITL0; SCHED0;
    __builtin_amdgcn_s_setprio(1);
#pragma unroll
    for (int i = 0; i < 2; ++i)
#pragma unroll
      for (int j = 0; j < 4; ++j)
#pragma unroll
        for (int k = 0; k < 2; ++k)
          acc[i][j] = __builtin_amdgcn_mfma_f32_16x16x32_bf16(a01[i][k], bf[j][k], acc[i][j], 0, 0, 0);
    __builtin_amdgcn_s_setprio(0);
    BARX;

#pragma unroll
    for (int i = 0; i < 2; ++i) {
      a23[i][0] = *(const short8*)&Ac[rA[2 + i] + slA0];
      a23[i][1] = *(const short8*)&Ac[rA[2 + i] + slA1];
    }
    if (pf) { stA(kt + 2, nb, 3); stB(kt + 2, nb, 0); stB(kt + 2, nb, 1); }
    BARX;
    WAITL0; SCHED0;
    __builtin_amdgcn_s_setprio(1);
#pragma unroll
    for (int i = 0; i < 2; ++i)
#pragma unroll
      for (int j = 0; j < 4; ++j)
#pragma unroll
        for (int k = 0; k < 2; ++k)
          acc[2 + i][j] = __builtin_amdgcn_mfma_f32_16x16x32_bf16(a23[i][k], bf[j][k], acc[2 + i][j], 0, 0, 0);
    __builtin_amdgcn_s_setprio(0);
    if (kt < NT - 2) { WAITV6; }
    else if (kt == NT - 2) { WAITV0; }
    BARX;

    cb = (cb == 2) ? 0 : cb + 1;
    nb = (nb == 2) ? 0 : nb + 1;
  }

  if (EPI == 1) {
    float* O = (float*)dq;
#pragma unroll
    for (int i = 0; i < 4; ++i)
#pragma unroll
      for (int j = 0; j < 4; ++j) {
        int col = n0 + wn * 64 + j * 16 + ln15;
        int m = m0 + wm * 64 + i * 16 + lq * 4;
#pragma unroll
        for (int r = 0; r < 4; ++r)
          O[(size_t)(m + r) * HIDc + col] = acc[i][j][r];
      }
  } else {  // EPI == 2: V-transpose epilogue, N = 2048
    unsigned short* V = (unsigned short*)dq;
#pragma unroll
    for (int i = 0; i < 4; ++i)
#pragma unroll
      for (int j = 0; j < 4; ++j) {
        int col = n0 + wn * 64 + j * 16 + ln15;   // 0..2047
        int h = col >> 7, d = col & 127;
        int m = m0 + wm * 64 + i * 16 + lq * 4;
        int b = m >> 11, s = m & 2047;
        us4 pk;
#pragma unroll
        for (int r = 0; r < 4; ++r) pk[r] = f2bf(acc[i][j][r]);
        *(us4*)(V + (((size_t)b * NHc + h) * HDc + d) * SS + s) = pk;
      }
  }
}

// ---------------------------------------------------------------------------
// 3) causal flash attention v9 (R13 structure, unchanged)
// ---------------------------------------------------------------------------
__global__ void __launch_bounds__(512, 2) attn_kernel(
    const unsigned short* __restrict__ Qg,
    const unsigned short* __restrict__ Kg,
    const unsigned short* __restrict__ Vg,   // [b][h][d][s]
    unsigned short* __restrict__ Og)
{
  __shared__ __align__(16) unsigned short Klds[3][64 * 128];   // [kv][d] swizzled
  __shared__ __align__(16) unsigned short Vlds[3][128 * 64];   // [d][kv] swizzled
  __shared__ __align__(16) unsigned short Plds[8][32 * 64];    // per-wave [q][kv] swizzled
  const int tid = threadIdx.x, lane = tid & 63, w = tid >> 6;
  const int l31 = lane & 31, hi = lane >> 5;

  const int wg = blockIdx.x;
  const int xcd = wg & 7, idx = wg >> 3;
  const int bh = xcd + 8 * (idx & 3);
  const int tt = idx >> 2;                   // 0..7

  const int qtile = (w < 2) ? tt : (w < 4) ? (tt + 8) : (w < 6) ? (31 - tt) : (23 - tt);
  const int sub1 = w & 1;
  const int q0w = qtile * 64 + sub1 * 32;
  const int ntiles = 32 - tt;                // >= 25

  const size_t hbase = (size_t)bh * SS * HDc;
  const float CE = 1.44269504089f * 0.08838834764831845f;  // log2(e)/sqrt(128)
  const int b = bh >> 4, h = bh & 15;

  short8 qf[8];
#pragma unroll
  for (int ks = 0; ks < 8; ++ks)
    qf[ks] = *(const short8*)(Qg + hbase + (size_t)(q0w + l31) * HDc + ks * 16 + hi * 8);

  f32x16 accO[4];
#pragma unroll
  for (int db = 0; db < 4; ++db)
#pragma unroll
    for (int r = 0; r < 16; ++r) accO[db][r] = 0.f;
  float mr = -1e30f, lr = 0.f;

  auto stage = [&](int kvt, int buf) {
    const int kv0 = kvt * 64;
#pragma unroll
    for (int p = 0; p < 2; ++p) {
      int c = p * 512 + tid;                 // 0..1023
      int krow = c >> 4, ksl = c & 15;
      gload_lds16(Kg + hbase + (size_t)(kv0 + krow) * HDc + ((ksl ^ (krow & 7)) << 3),
                  (unsigned short*)&Klds[buf][0] + (size_t)c * 8);
      int vd = c >> 3, vsl = c & 7;
      gload_lds16(Vg + hbase + (size_t)vd * SS + kv0 + ((vsl ^ (vd & 7)) << 3),
                  (unsigned short*)&Vlds[buf][0] + (size_t)c * 8);
    }
  };

  stage(0, 0); stage(1, 1);
  WAITV4; BARX;

  for (int kvt = 0; kvt < ntiles; ++kvt) {
    if (kvt + 2 < ntiles) stage(kvt + 2, (kvt + 2) % 3);
    const int cur = kvt % 3;

    if (kvt <= qtile) {
      const bool diag = (kvt == qtile);
      const bool haveT1 = (!diag) || sub1;

      f32x16 s0, s1;
#pragma unroll
      for (int r = 0; r < 16; ++r) s0[r] = 0.f;
      __builtin_amdgcn_s_setprio(1);
#pragma unroll
      for (int ks = 0; ks < 8; ++ks) {
        int row = l31;
        short8 kf = *(const short8*)&Klds[cur][row * 128 + (((2 * ks + hi) ^ (row & 7)) << 3)];
        s0 = __builtin_amdgcn_mfma_f32_32x32x16_bf16(kf, qf[ks], s0, 0, 0, 0);
      }
      if (haveT1) {
#pragma unroll
        for (int r = 0; r < 16; ++r) s1[r] = 0.f;
#pragma unroll
        for (int ks = 0; ks < 8; ++ks) {
          int row = 32 + l31;
          short8 kf = *(const short8*)&Klds[cur][row * 128 + (((2 * ks + hi) ^ (row & 7)) << 3)];
          s1 = __builtin_amdgcn_mfma_f32_32x32x16_bf16(kf, qf[ks], s1, 0, 0, 0);
        }
      }
      __builtin_amdgcn_s_setprio(0);

      if (diag) {
        if (sub1) {
#pragma unroll
          for (int r = 0; r < 16; ++r)
            if (((r & 3) + 8 * (r >> 2) + 4 * hi) > l31) s1[r] = -1e30f;
        } else {
#pragma unroll
          for (int r = 0; r < 16; ++r)
            if (((r & 3) + 8 * (r >> 2) + 4 * hi) > l31) s0[r] = -1e30f;
        }
      }

      float pmax = s0[0];
#pragma unroll
      for (int r = 1; r < 16; ++r) pmax = fmaxf(pmax, s0[r]);
      if (haveT1) {
#pragma unroll
        for (int r = 0; r < 16; ++r) pmax = fmaxf(pmax, s1[r]);
      }
      pmax = fmaxf(pmax, __shfl_xor(pmax, 32));

      int grow = (CE * (pmax - mr) > 8.0f) ? 1 : 0;
      if (__any(grow)) {
        float mn = fmaxf(mr, pmax);
        float al = exp2f(CE * (mr - mn));
        mr = mn; lr *= al;
        float alr[16];
#pragma unroll
        for (int r = 0; r < 16; ++r)
          alr[r] = __shfl(al, (r & 3) + 8 * (r >> 2) + 4 * hi);
#pragma unroll
        for (int db = 0; db < 4; ++db)
#pragma unroll
          for (int r = 0; r < 16; ++r) accO[db][r] *= alr[r];
      }

      float psum = 0.f;
#pragma unroll
      for (int r = 0; r < 16; ++r) {
        float p = exp2f(CE * (s0[r] - mr));
        s0[r] = p; psum += p;
      }
      if (haveT1) {
#pragma unroll
        for (int r = 0; r < 16; ++r) {
          float p = exp2f(CE * (s1[r] - mr));
          s1[r] = p; psum += p;
        }
      }
      psum += __shfl_xor(psum, 32);
      lr += psum;

#pragma unroll
      for (int i = 0; i < 4; ++i) {
        uint2v pk;
        pk[0] = cvtpk_bf16(s0[4 * i], s0[4 * i + 1]);
        pk[1] = cvtpk_bf16(s0[4 * i + 2], s0[4 * i + 3]);
        int chunk = i ^ (l31 & 7);
        *(uint2v*)&Plds[w][l31 * 64 + chunk * 8 + hi * 4] = pk;
      }
      if (haveT1) {
#pragma unroll
        for (int i = 0; i < 4; ++i) {
          uint2v pk;
          pk[0] = cvtpk_bf16(s1[4 * i], s1[4 * i + 1]);
          pk[1] = cvtpk_bf16(s1[4 * i + 2], s1[4 * i + 3]);
          int chunk = (4 + i) ^ (l31 & 7);
          *(uint2v*)&Plds[w][l31 * 64 + chunk * 8 + hi * 4] = pk;
        }
      }

      short8 ap[4];
#pragma unroll
      for (int ks = 0; ks < 2; ++ks)
        ap[ks] = *(const short8*)&Plds[w][l31 * 64 + (((2 * ks + hi) ^ (l31 & 7)) << 3)];
      if (haveT1) {
#pragma unroll
        for (int ks = 2; ks < 4; ++ks)
          ap[ks] = *(const short8*)&Plds[w][l31 * 64 + (((2 * ks + hi) ^ (l31 & 7)) << 3)];
      }

      __builtin_amdgcn_s_setprio(1);
#pragma unroll
      for (int db = 0; db < 4; ++db) {
        int row = db * 32 + l31;
#pragma unroll
        for (int ks = 0; ks < 2; ++ks) {
          short8 vf = *(const short8*)&Vlds[cur][row * 64 + (((2 * ks + hi) ^ (row & 7)) << 3)];
          accO[db] = __builtin_amdgcn_mfma_f32_32x32x16_bf16(ap[ks], vf, accO[db], 0, 0, 0);
        }
      }
      if (haveT1) {
#pragma unroll
        for (int db = 0; db < 4; ++db) {
          int row = db * 32 + l31;
#pragma unroll
          for (int ks = 2; ks < 4; ++ks) {
            short8 vf = *(const short8*)&Vlds[cur][row * 64 + (((2 * ks + hi) ^ (row & 7)) << 3)];
            accO[db] = __builtin_amdgcn_mfma_f32_32x32x16_bf16(ap[ks], vf, accO[db], 0, 0, 0);
          }
        }
      }
      __builtin_amdgcn_s_setprio(0);
    }

    if (kvt < ntiles - 2) { WAITV4; } else { WAITV0; }
    BARX;
  }

  float il = 1.0f / lr;
  float ilr[16];
#pragma unroll
  for (int r = 0; r < 16; ++r)
    ilr[r] = __shfl(il, (r & 3) + 8 * (r >> 2) + 4 * hi);
#pragma unroll
  for (int db = 0; db < 4; ++db)
#pragma unroll
    for (int r = 0; r < 16; ++r) {
      int q = q0w + (r & 3) + 8 * (r >> 2) + 4 * hi;
      int d = db * 32 + l31;
      Og[((size_t)b * SS + q) * HIDc + h * HDc + d] = f2bf(accO[db][r] * ilr[r]);
    }
}

// ---------------------------------------------------------------------------
extern "C" void kernel_launch(void* const* d_in, const int* in_sizes, int n_in,
                              void* d_out, int out_size, void* d_ws, size_t ws_size,
                              hipStream_t stream)
{
  if (ws_size < WS_NEED) return;

  const float* H  = (const float*)d_in[0];
  const float* Wq = (const float*)d_in[1];
  const float* Wk = (const float*)d_in[2];
  const float* Wv = (const float*)d_in[3];
  const float* Wo = (const float*)d_in[4];
  char* ws = (char*)d_ws;
  unsigned short* HB = (unsigned short*)(ws + OFF_HB);
  unsigned short* WB = (unsigned short*)(ws + OFF_WB);
  unsigned short* Qb = (unsigned short*)(ws + OFF_Q);
  unsigned short* Kb = (unsigned short*)(ws + OFF_K);
  unsigned short* Vb = (unsigned short*)(ws + OFF_V);
  unsigned short* AT = (unsigned short*)(ws + OFF_ATT);
  float* cosT = (float*)(ws + OFF_COS);
  float* sinT = (float*)(ws + OFF_SIN);

  cvt_kernel<<<12544, 256, 0, stream>>>(H, Wq, Wk, Wv, Wo, HB, cosT, sinT);
  // QK: 8-phase 256x256, folded N = 4096 -> grid 8 * 2 * 16 = 256 (1 round)
  gemm8p<16><<<256, 512, 0, stream>>>(HB, WB, Qb, Kb, Vb, cosT, sinT);
  // V: 2-phase 256x128, N = 2048 -> 256 blocks (1 round), V-transpose epilogue
  gemm8<2, 16><<<256, 512, 0, stream>>>(HB, WB + (size_t)2 * HIDc * KC,
                                        Vb, nullptr, nullptr, nullptr, nullptr);
  attn_kernel<<<256, 512, 0, stream>>>(Qb, Kb, Vb, AT);
  // proj: N = 2048 -> grid 8 * 2 * 16 = 256 (1 round)
  gemm8<1, 16><<<256, 512, 0, stream>>>(AT, WB + (size_t)3 * HIDc * KC,
                                        d_out, nullptr, nullptr, nullptr, nullptr);
}

// Round 16
// 238.537 us; speedup vs baseline: 1.2259x; 1.0214x over previous
//
#include <hip/hip_runtime.h>
#include <math.h>

typedef __attribute__((ext_vector_type(8))) short short8;
typedef __attribute__((ext_vector_type(4))) float f32x4;
typedef __attribute__((ext_vector_type(16))) float f32x16;
typedef __attribute__((ext_vector_type(4))) float fvec4;
typedef __attribute__((ext_vector_type(4))) unsigned short us4;
typedef __attribute__((ext_vector_type(2))) unsigned int uint2v;

#define DI __device__ __forceinline__
#define BARX asm volatile("s_barrier" ::: "memory")
#define WAITV6 asm volatile("s_waitcnt vmcnt(6)" ::: "memory")
#define WAITV0 asm volatile("s_waitcnt vmcnt(0)" ::: "memory")
#define WAITL0 asm volatile("s_waitcnt lgkmcnt(0)" ::: "memory")
#define SCHED0 __builtin_amdgcn_sched_barrier(0)

constexpr int BB = 2, SS = 2048, HIDc = 2048, NHc = 16, HDc = 128;
constexpr int MT = BB * SS;     // 4096 tokens
constexpr int KC = HIDc;        // 2048 inner dim

// ---- workspace layout (bytes) ----
constexpr size_t OFF_HB  = 0;                                      // H bf16   [4096][2048]
constexpr size_t OFF_WB  = OFF_HB + (size_t)MT * KC * 2;           // W bf16   4x[2048][2048]
constexpr size_t OFF_Q   = OFF_WB + (size_t)4 * HIDc * KC * 2;     // Q bf16   [b][h][s][d]
constexpr size_t OFF_K   = OFF_Q  + (size_t)BB * NHc * SS * HDc * 2;
constexpr size_t OFF_V   = OFF_K  + (size_t)BB * NHc * SS * HDc * 2; // V bf16 [b][h][d][s]
constexpr size_t OFF_ATT = OFF_V  + (size_t)BB * NHc * SS * HDc * 2; // attn bf16 [b*s][hid]
constexpr size_t OFF_COS = OFF_ATT + (size_t)MT * HIDc * 2;
constexpr size_t OFF_SIN = OFF_COS + (size_t)SS * 32 * 4;
constexpr size_t WS_NEED = OFF_SIN + (size_t)SS * 32 * 4;          // ~118 MB

DI float bf2f(unsigned short u) { union { unsigned u; float f; } v; v.u = (unsigned)u << 16; return v.f; }
DI unsigned short f2bf(float f) {
  union { float f; unsigned u; } v; v.f = f;
  unsigned r = v.u + 0x7fffu + ((v.u >> 16) & 1u);
  return (unsigned short)(r >> 16);
}

DI void gload_lds16(const void* g, void* l) {
  __builtin_amdgcn_global_load_lds((const __attribute__((address_space(1))) void*)g,
                                   (__attribute__((address_space(3))) void*)l, 16, 0, 0);
}

DI unsigned cvtpk_bf16(float lo, float hi_) {
  unsigned r;
  asm("v_cvt_pk_bf16_f32 %0, %1, %2" : "=v"(r) : "v"(lo), "v"(hi_));
  return r;
}

// ---------------------------------------------------------------------------
// 1) fp32 -> bf16 convert of H and the 4 weights + RoPE tables (fused tail)
// ---------------------------------------------------------------------------
__global__ void __launch_bounds__(256) cvt_kernel(
    const float* __restrict__ H,  const float* __restrict__ W0,
    const float* __restrict__ W1, const float* __restrict__ W2,
    const float* __restrict__ W3, unsigned short* __restrict__ dst,
    float* __restrict__ cosT, float* __restrict__ sinT)
{
  constexpr size_t HN = (size_t)MT * KC;      // 8388608
  constexpr size_t WN = (size_t)HIDc * KC;    // 4194304 = 2^22
  if (blockIdx.x >= 12288) {                  // RoPE-table tail blocks
    int idx = (blockIdx.x - 12288) * 256 + threadIdx.x;   // S*32 = 65536
    int t = idx >> 5, fi = idx & 31;
    float inv = powf(10000.0f, -(float)fi * (1.0f / 32.0f));
    float ang = (float)t * inv;
    cosT[idx] = cosf(ang);
    sinT[idx] = sinf(ang);
    return;
  }
  size_t e0 = ((size_t)blockIdx.x * 256 + threadIdx.x) * 8;
  const float* src; size_t off;
  if (e0 < HN) { src = H; off = e0; }
  else {
    size_t t = e0 - HN; int a = (int)(t >> 22);
    src = (a == 0) ? W0 : (a == 1) ? W1 : (a == 2) ? W2 : W3;
    off = t & (WN - 1);
  }
  fvec4 v0 = *(const fvec4*)(src + off);
  fvec4 v1 = *(const fvec4*)(src + off + 4);
  short8 o;
  o[0] = (short)f2bf(v0[0]); o[1] = (short)f2bf(v0[1]);
  o[2] = (short)f2bf(v0[2]); o[3] = (short)f2bf(v0[3]);
  o[4] = (short)f2bf(v1[0]); o[5] = (short)f2bf(v1[1]);
  o[6] = (short)f2bf(v1[2]); o[7] = (short)f2bf(v1[3]);
  *(short8*)(dst + e0) = o;
}

// ---------------------------------------------------------------------------
// 2a) QK GEMM — 8-phase half-tile pipelined (R14 structure, unchanged).
// ---------------------------------------------------------------------------
template<int NBX>
__global__ void __launch_bounds__(512, 2) gemm8p(
    const unsigned short* __restrict__ A,
    const unsigned short* __restrict__ Bw,
    void* __restrict__ dq, void* __restrict__ dk, void* __restrict__ dv,
    const float* __restrict__ cosT, const float* __restrict__ sinT)
{
  __shared__ __align__(16) unsigned short SL[8][128 * 64];  // 128 KiB
  const int tid = threadIdx.x, lane = tid & 63, w = tid >> 6;
  const int wm = w >> 2, wn = w & 3;        // 2m x 4n
  const int ln15 = lane & 15, lq = lane >> 4;

  const int xcd = blockIdx.x & 7, idx = blockIdx.x >> 3;
  const int by = xcd * 2 + idx / NBX, bx = idx % NBX;
  const int m0 = by * 256, n0 = bx * 256;

  const int srow = tid >> 3;
  const int sc = (tid & 7) ^ (srow & 7);
  const unsigned short* Ab = A  + ((size_t)m0 + srow) * KC + sc * 8;
  const unsigned short* Bb = Bw + ((size_t)n0 + srow) * KC + sc * 8;

  constexpr int NT = KC / 64;               // 32 K-tiles
  auto stage = [&](int kt, bool isA, int half, int buf) {
    if (kt >= NT) return;
    const unsigned short* s = (isA ? Ab : Bb) + (size_t)(half * 128) * KC + kt * 64;
    int slot = (isA ? 0 : 4) + buf * 2 + half;
    unsigned short* d = &SL[slot][(size_t)(w * 64) * 8];
    gload_lds16(s, d);
    gload_lds16(s + (size_t)64 * KC, d + (size_t)512 * 8);
  };

  auto readA = [&](int buf, int q, int i, int ks) -> short8 {
    int rl = ((q & 1) << 6) + (i << 5) + (wm << 4) + ln15;
    return *(const short8*)&SL[buf * 2 + (q >> 1)]
        [rl * 64 + ((((ks << 2) + lq) ^ (rl & 7)) << 3)];
  };
  auto readB = [&](int buf, int j, int ks) -> short8 {
    int rl = ((wn & 1) << 6) + (j << 4) + ln15;
    return *(const short8*)&SL[4 + buf * 2 + (wn >> 1)]
        [rl * 64 + ((((ks << 2) + lq) ^ (rl & 7)) << 3)];
  };

  stage(0, true, 0, 0); stage(0, true, 1, 0);
  stage(0, false, 0, 0); stage(0, false, 1, 0);
  stage(1, false, 0, 1); stage(1, false, 1, 1); stage(1, true, 0, 1);
  WAITV6; BARX;

  f32x4 acc[8][4] = {};
  short8 bfr[4][2];
  constexpr int NIT = NT / 2;               // 16 iterations x 2 K-tiles
  for (int t = 0; t < NIT; ++t) {
    const int k2 = 2 * t + 2, k3 = 2 * t + 3;
#pragma unroll
    for (int b = 0; b < 2; ++b) {
#pragma unroll
      for (int q = 0; q < 4; ++q) {
        short8 af[2][2];
#pragma unroll
        for (int i = 0; i < 2; ++i)
#pragma unroll
          for (int ks = 0; ks < 2; ++ks) af[i][ks] = readA(b, q, i, ks);
        if (q == 0) {
#pragma unroll
          for (int j = 0; j < 4; ++j)
#pragma unroll
            for (int ks = 0; ks < 2; ++ks) bfr[j][ks] = readB(b, j, ks);
        }
        if (b == 0) {
          if (q == 0) stage(2 * t + 1, true, 1, 1);
          else if (q == 1) stage(k2, false, 0, 0);
          else if (q == 2) stage(k2, false, 1, 0);
          else stage(k2, true, 0, 0);
        } else {
          if (q == 0) stage(k2, true, 1, 0);
          else if (q == 1) stage(k3, false, 0, 1);
          else if (q == 2) stage(k3, false, 1, 1);
          else stage(k3, true, 0, 1);
        }
        BARX;
        WAITL0; SCHED0;
        __builtin_amdgcn_s_setprio(1);
#pragma unroll
        for (int i = 0; i < 2; ++i)
#pragma unroll
          for (int j = 0; j < 4; ++j)
#pragma unroll
            for (int ks = 0; ks < 2; ++ks)
              acc[2 * q + i][j] = __builtin_amdgcn_mfma_f32_16x16x32_bf16(
                  af[i][ks], bfr[j][ks], acc[2 * q + i][j], 0, 0, 0);
        __builtin_amdgcn_s_setprio(0);
        if (q == 3) { if (t == NIT - 1) { WAITV0; } else { WAITV6; } }
        BARX;
      }
    }
  }

  // ---- folded-N epilogue with fused RoPE (z in {0,1} for N=4096) ----
#pragma unroll
  for (int f = 0; f < 8; ++f)
#pragma unroll
    for (int j = 0; j < 4; ++j) {
      int col = n0 + wn * 64 + j * 16 + ln15;
      int z = col >> 11;
      int c2 = col & 2047;
      int h = c2 >> 7, d = c2 & 127;
      int m = m0 + 32 * f + 16 * wm + lq * 4;
      int b = m >> 11, s = m & 2047;
      if (z == 2) {
        us4 pk;
#pragma unroll
        for (int r = 0; r < 4; ++r) pk[r] = f2bf(acc[f][j][r]);
        *(us4*)((unsigned short*)dv + (((size_t)b * NHc + h) * HDc + d) * SS + s) = pk;
      } else {
        unsigned short* D = (unsigned short*)(z ? dk : dq);
        const int fi = (d >> 1) & 31;
        const bool odd = (d & 1) != 0;
#pragma unroll
        for (int r = 0; r < 4; ++r) {
          float v = acc[f][j][r];
          float p = __shfl_xor(v, 1);
          float cs = cosT[(size_t)(s + r) * 32 + fi];
          float sn = sinT[(size_t)(s + r) * 32 + fi];
          float y = odd ? (p * sn + v * cs) : (v * cs - p * sn);
          D[(((size_t)b * NHc + h) * SS + s + r) * HDc + d] = f2bf(y);
        }
      }
    }
}

// ---------------------------------------------------------------------------
// 2b) Pipelined bf16 GEMM (R8 structure): BM=256 BN=128 BK=64, 3-deep ring,
//     distance-2 prefetch, counted vmcnt(6). EPI 1: fp32 (proj). EPI 2: V-T.
// ---------------------------------------------------------------------------
template<int EPI, int NBX>
__global__ void __launch_bounds__(512, 2) gemm8(
    const unsigned short* __restrict__ A,
    const unsigned short* __restrict__ Bw,
    void* __restrict__ dq, void* __restrict__ dk, void* __restrict__ dv,
    const float* __restrict__ cosT, const float* __restrict__ sinT)
{
  __shared__ __align__(16) unsigned short Al[3][256 * 64];
  __shared__ __align__(16) unsigned short Bl[3][128 * 64];
  const int tid = threadIdx.x, lane = tid & 63, w = tid >> 6;
  const int wm = w >> 1, wn = w & 1;
  const int ln15 = lane & 15, lq = lane >> 4;

  const int xcd = blockIdx.x & 7, idx = blockIdx.x >> 3;
  const int by = xcd * 2 + idx / NBX, bx = idx % NBX;
  const int m0 = by * 256, n0 = bx * 128;

  const int srow = tid >> 3;                 // 0..63
  const int sc = (tid & 7) ^ (srow & 7);
  const unsigned short* asrc[4];
  const unsigned short* bsrc[2];
#pragma unroll
  for (int l = 0; l < 4; ++l) asrc[l] = A  + (size_t)(m0 + l * 64 + srow) * KC + sc * 8;
#pragma unroll
  for (int l = 0; l < 2; ++l) bsrc[l] = Bw + (size_t)(n0 + l * 64 + srow) * KC + sc * 8;

  const int x7 = ln15 & 7;
  const int slA0 = (lq ^ x7) * 8;
  const int slA1 = ((4 + lq) ^ x7) * 8;
  int rA[4], rB[4];
#pragma unroll
  for (int i = 0; i < 4; ++i) rA[i] = (wm * 64 + i * 16 + ln15) * 64;
#pragma unroll
  for (int j = 0; j < 4; ++j) rB[j] = (wn * 64 + j * 16 + ln15) * 64;

  constexpr int NT = KC / 64;   // 32
  auto stA = [&](int kt, int buf, int l) {
    gload_lds16(asrc[l] + (size_t)kt * 64, &Al[buf][(size_t)(l * 512 + w * 64) * 8]);
  };
  auto stB = [&](int kt, int buf, int l) {
    gload_lds16(bsrc[l] + (size_t)kt * 64, &Bl[buf][(size_t)(l * 512 + w * 64) * 8]);
  };

  stA(0, 0, 0); stA(0, 0, 1); stA(0, 0, 2); stA(0, 0, 3); stB(0, 0, 0); stB(0, 0, 1);
  stA(1, 1, 0); stA(1, 1, 1); stA(1, 1, 2); stA(1, 1, 3); stB(1, 1, 0); stB(1, 1, 1);
  WAITV6; BARX;

  f32x4 acc[4][4] = {};
  int cb = 0, nb = 2;
  for (int kt = 0; kt < NT; ++kt) {
    const unsigned short* Ac = &Al[cb][0];
    const unsigned short* Bc = &Bl[cb][0];
    const bool pf = (kt + 2 < NT);
    short8 a01[2][2], a23[2][2], bf[4][2];

#pragma unroll
    for (int i = 0; i < 2; ++i) {
      a01[i][0] = *(const short8*)&Ac[rA[i] + slA0];
      a01[i][1] = *(const short8*)&Ac[rA[i] + slA1];
    }
#pragma unroll
    for (int j = 0; j < 4; ++j) {
      bf[j][0] = *(const short8*)&Bc[rB[j] + slA0];
      bf[j][1] = *(const short8*)&Bc[rB[j] + slA1];
    }
    if (pf) { stA(kt + 2, nb, 0); stA(kt + 2, nb, 1); stA(kt + 2, nb, 2); }
    BARX;
    WAITL0; SCHED0;
    __builtin_amdgcn_s_setprio(1);
#pragma unroll
    for (int i = 0; i < 2; ++i)
#pragma unroll
      for (int j = 0; j < 4; ++j)
#pragma unroll
        for (int k = 0; k < 2; ++k)
          acc[i][j] = __builtin_amdgcn_mfma_f32_16x16x32_bf16(a01[i][k], bf[j][k], acc[i][j], 0, 0, 0);
    __builtin_amdgcn_s_setprio(0);
    BARX;

#pragma unroll
    for (int i = 0; i < 2; ++i) {
      a23[i][0] = *(const short8*)&Ac[rA[2 + i] + slA0];
      a23[i][1] = *(const short8*)&Ac[rA[2 + i] + slA1];
    }
    if (pf) { stA(kt + 2, nb, 3); stB(kt + 2, nb, 0); stB(kt + 2, nb, 1); }
    BARX;
    WAITL0; SCHED0;
    __builtin_amdgcn_s_setprio(1);
#pragma unroll
    for (int i = 0; i < 2; ++i)
#pragma unroll
      for (int j = 0; j < 4; ++j)
#pragma unroll
        for (int k = 0; k < 2; ++k)
          acc[2 + i][j] = __builtin_amdgcn_mfma_f32_16x16x32_bf16(a23[i][k], bf[j][k], acc[2 + i][j], 0, 0, 0);
    __builtin_amdgcn_s_setprio(0);
    if (kt < NT - 2) { WAITV6; }
    else if (kt == NT - 2) { WAITV0; }
    BARX;

    cb = (cb == 2) ? 0 : cb + 1;
    nb = (nb == 2) ? 0 : nb + 1;
  }

  if (EPI == 1) {
    float* O = (float*)dq;
#pragma unroll
    for (int i = 0; i < 4; ++i)
#pragma unroll
      for (int j = 0; j < 4; ++j) {
        int col = n0 + wn * 64 + j * 16 + ln15;
        int m = m0 + wm * 64 + i * 16 + lq * 4;
#pragma unroll
        for (int r = 0; r < 4; ++r)
          O[(size_t)(m + r) * HIDc + col] = acc[i][j][r];
      }
  } else {  // EPI == 2: V-transpose epilogue, N = 2048
    unsigned short* V = (unsigned short*)dq;
#pragma unroll
    for (int i = 0; i < 4; ++i)
#pragma unroll
      for (int j = 0; j < 4; ++j) {
        int col = n0 + wn * 64 + j * 16 + ln15;   // 0..2047
        int h = col >> 7, d = col & 127;
        int m = m0 + wm * 64 + i * 16 + lq * 4;
        int b = m >> 11, s = m & 2047;
        us4 pk;
#pragma unroll
        for (int r = 0; r < 4; ++r) pk[r] = f2bf(acc[i][j][r]);
        *(us4*)(V + (((size_t)b * NHc + h) * HDc + d) * SS + s) = pk;
      }
  }
}

// ---------------------------------------------------------------------------
// 3) causal flash attention v10 — KVBLK=128: two 64-kv sub-tiles per barrier
//    interval (halves barrier convoy; adjacent sub-tile chains overlap).
//    8-wave SIMD-complementary blocks (R10), distance-1 dbuf (R10 scheme),
//    per-wave 2KB P region reused per 32-kv half (in-order DS ops).
//    LDS = K 2x32K + V 2x32K + P 16K = 144 KiB.
// ---------------------------------------------------------------------------
__global__ void __launch_bounds__(512, 2) attn_kernel(
    const unsigned short* __restrict__ Qg,
    const unsigned short* __restrict__ Kg,
    const unsigned short* __restrict__ Vg,   // [b][h][d][s]
    unsigned short* __restrict__ Og)
{
  __shared__ __align__(16) unsigned short Klds[2][128 * 128];  // [kv][d] swz
  __shared__ __align__(16) unsigned short Vlds[2][128 * 128];  // [d][kv] swz
  __shared__ __align__(16) unsigned short Plds[8][32 * 32];    // per-wave 2KB
  const int tid = threadIdx.x, lane = tid & 63, w = tid >> 6;
  const int l31 = lane & 31, hi = lane >> 5;

  const int wg = blockIdx.x;
  const int xcd = wg & 7, idx = wg >> 3;
  const int bh = xcd + 8 * (idx & 3);
  const int tt = idx >> 2;                   // 0..7

  const int qtile = (w < 2) ? tt : (w < 4) ? (tt + 8) : (w < 6) ? (31 - tt) : (23 - tt);
  const int sub1 = w & 1;
  const int q0w = qtile * 64 + sub1 * 32;
  const int NT128 = (33 - tt) >> 1;          // covers kvt 0 .. 31-tt

  const size_t hbase = (size_t)bh * SS * HDc;
  const float CE = 1.44269504089f * 0.08838834764831845f;  // log2(e)/sqrt(128)
  const int b = bh >> 4, h = bh & 15;

  short8 qf[8];
#pragma unroll
  for (int ks = 0; ks < 8; ++ks)
    qf[ks] = *(const short8*)(Qg + hbase + (size_t)(q0w + l31) * HDc + ks * 16 + hi * 8);

  f32x16 accO[4];
#pragma unroll
  for (int db = 0; db < 4; ++db)
#pragma unroll
    for (int r = 0; r < 16; ++r) accO[db][r] = 0.f;
  float mr = -1e30f, lr = 0.f;

  // 512 threads: 4 K-chunks + 4 V-chunks per thread per 128-kv tile
  auto stage = [&](int T, int buf) {
    const int kv0 = T * 128;
#pragma unroll
    for (int p = 0; p < 4; ++p) {
      int c = p * 512 + tid;                 // 0..2047
      int krow = c >> 4, ksl = c & 15;       // K: [kv 128][d 128]
      gload_lds16(Kg + hbase + (size_t)(kv0 + krow) * HDc + ((ksl ^ (krow & 7)) << 3),
                  (unsigned short*)&Klds[buf][0] + (size_t)c * 8);
      int vd = c >> 4, vsl = c & 15;         // V: [d 128][kv 128]
      gload_lds16(Vg + hbase + (size_t)vd * SS + kv0 + ((vsl ^ (vd & 7)) << 3),
                  (unsigned short*)&Vlds[buf][0] + (size_t)c * 8);
    }
  };

  stage(0, 0);
  WAITV0; BARX;

  for (int T = 0; T < NT128; ++T) {
    const int cur = T & 1;
    if (T + 1 < NT128) stage(T + 1, cur ^ 1);

#pragma unroll
    for (int sub = 0; sub < 2; ++sub) {
      const int kvt = 2 * T + sub;
      if (kvt <= qtile) {
        const bool diag = (kvt == qtile);
        const bool haveT1 = (!diag) || sub1;

        // ---- swapped QK^T: D[k][q] ----
        f32x16 s0, s1;
#pragma unroll
        for (int r = 0; r < 16; ++r) s0[r] = 0.f;
        __builtin_amdgcn_s_setprio(1);
#pragma unroll
        for (int ks = 0; ks < 8; ++ks) {
          int row = sub * 64 + l31;
          short8 kf = *(const short8*)&Klds[cur][row * 128 + (((2 * ks + hi) ^ (row & 7)) << 3)];
          s0 = __builtin_amdgcn_mfma_f32_32x32x16_bf16(kf, qf[ks], s0, 0, 0, 0);
        }
        if (haveT1) {
#pragma unroll
          for (int r = 0; r < 16; ++r) s1[r] = 0.f;
#pragma unroll
          for (int ks = 0; ks < 8; ++ks) {
            int row = sub * 64 + 32 + l31;
            short8 kf = *(const short8*)&Klds[cur][row * 128 + (((2 * ks + hi) ^ (row & 7)) << 3)];
            s1 = __builtin_amdgcn_mfma_f32_32x32x16_bf16(kf, qf[ks], s1, 0, 0, 0);
          }
        }
        __builtin_amdgcn_s_setprio(0);

        if (diag) {                          // mask rowid > own q within 32-blk
          if (sub1) {
#pragma unroll
            for (int r = 0; r < 16; ++r)
              if (((r & 3) + 8 * (r >> 2) + 4 * hi) > l31) s1[r] = -1e30f;
          } else {
#pragma unroll
            for (int r = 0; r < 16; ++r)
              if (((r & 3) + 8 * (r >> 2) + 4 * hi) > l31) s0[r] = -1e30f;
          }
        }

        // ---- in-register online softmax ----
        float pmax = s0[0];
#pragma unroll
        for (int r = 1; r < 16; ++r) pmax = fmaxf(pmax, s0[r]);
        if (haveT1) {
#pragma unroll
          for (int r = 0; r < 16; ++r) pmax = fmaxf(pmax, s1[r]);
        }
        pmax = fmaxf(pmax, __shfl_xor(pmax, 32));

        int grow = (CE * (pmax - mr) > 8.0f) ? 1 : 0;
        if (__any(grow)) {
          float mn = fmaxf(mr, pmax);
          float al = exp2f(CE * (mr - mn));
          mr = mn; lr *= al;
          float alr[16];
#pragma unroll
          for (int r = 0; r < 16; ++r)
            alr[r] = __shfl(al, (r & 3) + 8 * (r >> 2) + 4 * hi);
#pragma unroll
          for (int db = 0; db < 4; ++db)
#pragma unroll
            for (int r = 0; r < 16; ++r) accO[db][r] *= alr[r];
        }

        float psum = 0.f;
#pragma unroll
        for (int r = 0; r < 16; ++r) {
          float p = exp2f(CE * (s0[r] - mr));
          s0[r] = p; psum += p;
        }
        if (haveT1) {
#pragma unroll
          for (int r = 0; r < 16; ++r) {
            float p = exp2f(CE * (s1[r] - mr));
            s1[r] = p; psum += p;
          }
        }
        psum += __shfl_xor(psum, 32);
        lr += psum;

        // ---- P half s0 (kv 0..31 of sub) -> 2KB region, PV ks 0..1 ----
#pragma unroll
        for (int i = 0; i < 4; ++i) {
          uint2v pk;
          pk[0] = cvtpk_bf16(s0[4 * i], s0[4 * i + 1]);
          pk[1] = cvtpk_bf16(s0[4 * i + 2], s0[4 * i + 3]);
          int c = i ^ (l31 & 3);
          *(uint2v*)&Plds[w][l31 * 32 + c * 8 + hi * 4] = pk;
        }
        {
          short8 ap0 = *(const short8*)&Plds[w][l31 * 32 + ((hi ^ (l31 & 3)) << 3)];
          short8 ap1 = *(const short8*)&Plds[w][l31 * 32 + (((2 + hi) ^ (l31 & 3)) << 3)];
          __builtin_amdgcn_s_setprio(1);
#pragma unroll
          for (int db = 0; db < 4; ++db) {
            int row = db * 32 + l31;
            short8 vf0 = *(const short8*)&Vlds[cur][row * 128 + ((sub * 8 + ((0 + hi) ^ (row & 7))) << 3)];
            short8 vf1 = *(const short8*)&Vlds[cur][row * 128 + ((sub * 8 + ((2 + hi) ^ (row & 7))) << 3)];
            accO[db] = __builtin_amdgcn_mfma_f32_32x32x16_bf16(ap0, vf0, accO[db], 0, 0, 0);
            accO[db] = __builtin_amdgcn_mfma_f32_32x32x16_bf16(ap1, vf1, accO[db], 0, 0, 0);
          }
          __builtin_amdgcn_s_setprio(0);
        }

        // ---- P half s1 (kv 32..63 of sub) -> same region, PV ks 2..3 ----
        if (haveT1) {
#pragma unroll
          for (int i = 0; i < 4; ++i) {
            uint2v pk;
            pk[0] = cvtpk_bf16(s1[4 * i], s1[4 * i + 1]);
            pk[1] = cvtpk_bf16(s1[4 * i + 2], s1[4 * i + 3]);
            int c = i ^ (l31 & 3);
            *(uint2v*)&Plds[w][l31 * 32 + c * 8 + hi * 4] = pk;
          }
          short8 ap0 = *(const short8*)&Plds[w][l31 * 32 + ((hi ^ (l31 & 3)) << 3)];
          short8 ap1 = *(const short8*)&Plds[w][l31 * 32 + (((2 + hi) ^ (l31 & 3)) << 3)];
          __builtin_amdgcn_s_setprio(1);
#pragma unroll
          for (int db = 0; db < 4; ++db) {
            int row = db * 32 + l31;
            short8 vf0 = *(const short8*)&Vlds[cur][row * 128 + ((sub * 8 + ((4 + hi) ^ (row & 7))) << 3)];
            short8 vf1 = *(const short8*)&Vlds[cur][row * 128 + ((sub * 8 + ((6 + hi) ^ (row & 7))) << 3)];
            accO[db] = __builtin_amdgcn_mfma_f32_32x32x16_bf16(ap0, vf0, accO[db], 0, 0, 0);
            accO[db] = __builtin_amdgcn_mfma_f32_32x32x16_bf16(ap1, vf1, accO[db], 0, 0, 0);
          }
          __builtin_amdgcn_s_setprio(0);
        }
      }
    }

    WAITV0; BARX;   // next tile staged & visible; buffers certified
  }

  float il = 1.0f / lr;
  float ilr[16];
#pragma unroll
  for (int r = 0; r < 16; ++r)
    ilr[r] = __shfl(il, (r & 3) + 8 * (r >> 2) + 4 * hi);
#pragma unroll
  for (int db = 0; db < 4; ++db)
#pragma unroll
    for (int r = 0; r < 16; ++r) {
      int q = q0w + (r & 3) + 8 * (r >> 2) + 4 * hi;
      int d = db * 32 + l31;
      Og[((size_t)b * SS + q) * HIDc + h * HDc + d] = f2bf(accO[db][r] * ilr[r]);
    }
}

// ---------------------------------------------------------------------------
extern "C" void kernel_launch(void* const* d_in, const int* in_sizes, int n_in,
                              void* d_out, int out_size, void* d_ws, size_t ws_size,
                              hipStream_t stream)
{
  if (ws_size < WS_NEED) return;

  const float* H  = (const float*)d_in[0];
  const float* Wq = (const float*)d_in[1];
  const float* Wk = (const float*)d_in[2];
  const float* Wv = (const float*)d_in[3];
  const float* Wo = (const float*)d_in[4];
  char* ws = (char*)d_ws;
  unsigned short* HB = (unsigned short*)(ws + OFF_HB);
  unsigned short* WB = (unsigned short*)(ws + OFF_WB);
  unsigned short* Qb = (unsigned short*)(ws + OFF_Q);
  unsigned short* Kb = (unsigned short*)(ws + OFF_K);
  unsigned short* Vb = (unsigned short*)(ws + OFF_V);
  unsigned short* AT = (unsigned short*)(ws + OFF_ATT);
  float* cosT = (float*)(ws + OFF_COS);
  float* sinT = (float*)(ws + OFF_SIN);

  cvt_kernel<<<12544, 256, 0, stream>>>(H, Wq, Wk, Wv, Wo, HB, cosT, sinT);
  // QK: 8-phase 256x256, folded N = 4096 -> grid 8 * 2 * 16 = 256 (1 round)
  gemm8p<16><<<256, 512, 0, stream>>>(HB, WB, Qb, Kb, Vb, cosT, sinT);
  // V: 2-phase 256x128, N = 2048 -> 256 blocks (1 round), V-transpose epilogue
  gemm8<2, 16><<<256, 512, 0, stream>>>(HB, WB + (size_t)2 * HIDc * KC,
                                        Vb, nullptr, nullptr, nullptr, nullptr);
  attn_kernel<<<256, 512, 0, stream>>>(Qb, Kb, Vb, AT);
  // proj: N = 2048 -> grid 8 * 2 * 16 = 256 (1 round)
  gemm8<1, 16><<<256, 512, 0, stream>>>(AT, WB + (size_t)3 * HIDc * KC,
                                        d_out, nullptr, nullptr, nullptr, nullptr);
}